// Round 6
// baseline (1683.714 us; speedup 1.0000x reference)
//
#include <hip/hip_runtime.h>
#include <math.h>

// Problem constants (fixed by the reference)
#define BN   8
#define NN   1024
#define FIN  256
#define HIDN 128
#define KTOP 513          // int(1024*0.5)+1
#define NITER 20          // opt_epochs in setup_inputs
#define EPS_S 0.01f
#define INV_EPS 100.0f
#define LOG_MU (-6.9314718055994531f)   // -log(1024)
#define SNB 256           // blocks in persistent sinkhorn kernel

typedef __attribute__((ext_vector_type(8))) short bfrag8;   // 8 bf16 (4 VGPR)
typedef __attribute__((ext_vector_type(4))) float facc4;    // MFMA accumulator

#define GLOAD16(g, l) __builtin_amdgcn_global_load_lds( \
    (const __attribute__((address_space(1))) unsigned int*)(g), \
    (__attribute__((address_space(3))) unsigned int*)(l), 16, 0, 0)

static __device__ __forceinline__ float wred_sum(float s) {
#pragma unroll
  for (int o = 32; o > 0; o >>= 1) s += __shfl_xor(s, o);
  return s;
}
static __device__ __forceinline__ float wred_max(float s) {
#pragma unroll
  for (int o = 32; o > 0; o >>= 1) s = fmaxf(s, __shfl_xor(s, o));
  return s;
}
static __device__ __forceinline__ unsigned short f2b(float f) {
  unsigned int u = __float_as_uint(f);
  u += 0x7fff + ((u >> 16) & 1);      // RNE
  return (unsigned short)(u >> 16);
}
static __device__ __forceinline__ float b2f(unsigned short h) {
  return __uint_as_float((unsigned int)h << 16);
}
static __device__ __forceinline__ float max4(float4 v) {
  return fmaxf(fmaxf(v.x, v.y), fmaxf(v.z, v.w));
}
static __device__ __forceinline__ float esum4(float4 a, float m) {
  return __expf(a.x - m) + __expf(a.y - m) + __expf(a.z - m) + __expf(a.w - m);
}

// ---- rowstats (4 rows/block): d = rsqrt(max(rowsum+1,1)), rmask ------------
// WRBF: also write bf16 copy; WCOPY: also write fp32 copy (new_adjs[0]).
template<int WRBF, int WCOPY>
__global__ __launch_bounds__(256) void k_rowstats4(const float* __restrict__ adj,
                                                   float* __restrict__ dv,
                                                   float* __restrict__ rm,
                                                   unsigned short* __restrict__ abf,
                                                   float* __restrict__ ocopy) {
  int r0 = blockIdx.x << 2;
  int t = threadIdx.x, lane = t & 63, wv = t >> 6;
  __shared__ float sm[4][4];
#pragma unroll
  for (int r = 0; r < 4; ++r) {
    float4 v = ((const float4*)(adj + (long)(r0 + r) * NN))[t];
    if (WRBF) {
      ushort4 h; h.x = f2b(v.x); h.y = f2b(v.y); h.z = f2b(v.z); h.w = f2b(v.w);
      *(ushort4*)(abf + (long)(r0 + r) * NN + t * 4) = h;
    }
    if (WCOPY) ((float4*)(ocopy + (long)(r0 + r) * NN))[t] = v;
    float s = (v.x + v.y) + (v.z + v.w);
    s = wred_sum(s);
    if (lane == 0) sm[wv][r] = s;
  }
  __syncthreads();
  if (t < 4) {
    float tot = sm[0][t] + sm[1][t] + sm[2][t] + sm[3][t];
    dv[r0 + t] = rsqrtf(fmaxf(tot + 1.0f, 1.0f));
    rm[r0 + t] = tot > 0.0f ? 1.0f : 0.0f;
  }
}

// ---------------- fp32 -> bf16 elementwise ----------------------------------
__global__ __launch_bounds__(256) void k_f2b(const float* __restrict__ X,
                                             unsigned short* __restrict__ Y) {
  long i = ((long)blockIdx.x * 256 + threadIdx.x) * 4;
  float4 v = *(const float4*)(X + i);
  Y[i] = f2b(v.x); Y[i + 1] = f2b(v.y); Y[i + 2] = f2b(v.z); Y[i + 3] = f2b(v.w);
}

// ---- W1 [256][128] fp32 -> W1t [128][256] bf16 -----------------------------
__global__ __launch_bounds__(256) void k_w1t(const float* __restrict__ W,
                                             unsigned short* __restrict__ Wt) {
  int idx = blockIdx.x * 256 + threadIdx.x;   // 32768
  int n = idx >> 8, k = idx & 255;
  Wt[idx] = f2b(W[k * HIDN + n]);
}

// ---- fp32 X -> bf16 hi + bf16 lo (split for 3-product MFMA) ---------------
__global__ __launch_bounds__(256) void k_split2(const float* __restrict__ X,
                                                unsigned short* __restrict__ Xh,
                                                unsigned short* __restrict__ Xl) {
  long i = ((long)blockIdx.x * 256 + threadIdx.x) * 4;
  float4 v = *(const float4*)(X + i);
  ushort4 h, l;
  h.x = f2b(v.x); l.x = f2b(v.x - b2f(h.x));
  h.y = f2b(v.y); l.y = f2b(v.y - b2f(h.y));
  h.z = f2b(v.z); l.z = f2b(v.z - b2f(h.z));
  h.w = f2b(v.w); l.w = f2b(v.w - b2f(h.w));
  *(ushort4*)(Xh + i) = h;
  *(ushort4*)(Xl + i) = l;
}

// ---------------- fp32 [R][C] -> bf16 [C][R] transpose ----------------------
__global__ __launch_bounds__(256) void k_transp(const float* __restrict__ X,
                                                unsigned short* __restrict__ Xt,
                                                int R, int C) {
  __shared__ float tile[64][65];
  long bb = blockIdx.z;
  const float* Xb = X + bb * (long)R * C;
  unsigned short* Xtb = Xt + bb * (long)R * C;
  int r0 = blockIdx.y * 64, c0 = blockIdx.x * 64;
  int t = threadIdx.x;
  int tr = t >> 4, tc4 = (t & 15) * 4;
#pragma unroll
  for (int p = 0; p < 4; ++p) {
    float4 v = *(const float4*)(Xb + (long)(r0 + tr + p * 16) * C + c0 + tc4);
    tile[tr + p * 16][tc4 + 0] = v.x; tile[tr + p * 16][tc4 + 1] = v.y;
    tile[tr + p * 16][tc4 + 2] = v.z; tile[tr + p * 16][tc4 + 3] = v.w;
  }
  __syncthreads();
  int jj = t >> 2, i0 = (t & 3) * 16;
  unsigned short* orow = Xtb + (long)(c0 + jj) * R + r0 + i0;
#pragma unroll
  for (int q = 0; q < 16; ++q) orow[q] = f2b(tile[i0 + q][jj]);
}

// ---- scale-transpose-cast: Bg[b][n][j] = bf16(d[b*1024+j]*XW[b][j][n]) -----
template<int SPLIT>
__global__ __launch_bounds__(256) void k_stc(const float* __restrict__ XW,
                                             const float* __restrict__ dvv,
                                             unsigned short* __restrict__ Bh,
                                             unsigned short* __restrict__ Bl,
                                             int F) {
  __shared__ float tile[64][65];
  __shared__ float dl[64];
  int bz = blockIdx.z;
  const float* Xb = XW + (long)bz * NN * F;
  int j0 = blockIdx.x * 64;   // node dim
  int n0 = blockIdx.y * 64;   // feature dim
  int t = threadIdx.x;
  int tr = t >> 4, tc4 = (t & 15) * 4;
#pragma unroll
  for (int p = 0; p < 4; ++p) {
    float4 v = *(const float4*)(Xb + (long)(j0 + tr + p * 16) * F + n0 + tc4);
    tile[tr + p * 16][tc4 + 0] = v.x; tile[tr + p * 16][tc4 + 1] = v.y;
    tile[tr + p * 16][tc4 + 2] = v.z; tile[tr + p * 16][tc4 + 3] = v.w;
  }
  if (t < 64) dl[t] = dvv[(bz << 10) + j0 + t];
  __syncthreads();
  int nn = t >> 2, i0 = (t & 3) * 16;
  long obase = ((long)bz * F + n0 + nn) * NN + j0 + i0;
#pragma unroll
  for (int q = 0; q < 16; ++q) {
    float v = tile[i0 + q][nn] * dl[i0 + q];
    unsigned short h = f2b(v);
    Bh[obase + q] = h;
    if (SPLIT) Bl[obase + q] = f2b(v - b2f(h));
  }
}

// ---------------- bf16 NT MFMA GEMM: C[m,n] = sum_k A[m,k]*B[n,k] -----------
// WBF: 0 none, 1 bf16, 2 bf16 hi+lo pair
template<int WF32, int WBF>
__global__ __launch_bounds__(256) void k_mfma_nt(
    const unsigned short* __restrict__ A, const unsigned short* __restrict__ B,
    float* __restrict__ Cf, unsigned short* __restrict__ Cb,
    unsigned short* __restrict__ Cb2,
    int K, int ldA, int ldB, int ldC, long sA, long sB, long sC) {
  __shared__ unsigned short As[128 * 32];
  __shared__ unsigned short Bs[128 * 32];
  int bz = blockIdx.z;
  A += bz * sA; B += bz * sB;
  int m0 = blockIdx.y * 128, n0 = blockIdx.x * 128;
  int tid = threadIdx.x, lane = tid & 63, w = tid >> 6;
  int wr = w >> 1, wc = w & 1;
  facc4 acc[4][4];
#pragma unroll
  for (int i = 0; i < 4; ++i)
#pragma unroll
    for (int j = 0; j < 4; ++j)
#pragma unroll
      for (int q = 0; q < 4; ++q) acc[i][j][q] = 0.f;

  int rA0 = w * 16 + (lane >> 2);
  int kslot = lane & 3;

  for (int k0 = 0; k0 < K; k0 += 32) {
#pragma unroll
    for (int i = 0; i < 2; ++i) {
      int row = i * 64 + rA0;
      int ks = (kslot ^ (row & 3)) << 3;   // pre-swizzled global source
      GLOAD16(A + (long)(m0 + row) * ldA + k0 + ks, As + (i * 64 + w * 16) * 32);
      GLOAD16(B + (long)(n0 + row) * ldB + k0 + ks, Bs + (i * 64 + w * 16) * 32);
    }
    __syncthreads();
    bfrag8 af[4], bfr[4];
#pragma unroll
    for (int mi = 0; mi < 4; ++mi) {
      int row = wr * 64 + mi * 16 + (lane & 15);
      int sl = (((lane >> 4) ^ (row & 3)) << 3);   // swizzled read
      af[mi] = *(const bfrag8*)(As + row * 32 + sl);
    }
#pragma unroll
    for (int ni = 0; ni < 4; ++ni) {
      int row = wc * 64 + ni * 16 + (lane & 15);
      int sl = (((lane >> 4) ^ (row & 3)) << 3);
      bfr[ni] = *(const bfrag8*)(Bs + row * 32 + sl);
    }
#pragma unroll
    for (int mi = 0; mi < 4; ++mi)
#pragma unroll
      for (int ni = 0; ni < 4; ++ni)
        acc[mi][ni] = __builtin_amdgcn_mfma_f32_16x16x32_bf16(
            af[mi], bfr[ni], acc[mi][ni], 0, 0, 0);
    __syncthreads();
  }
  if (WF32) Cf += bz * sC;
  if (WBF) Cb += bz * sC;
  if (WBF == 2) Cb2 += bz * sC;
#pragma unroll
  for (int mi = 0; mi < 4; ++mi) {
    int rowb = m0 + wr * 64 + mi * 16 + ((lane >> 4) << 2);
#pragma unroll
    for (int ni = 0; ni < 4; ++ni) {
      int col = n0 + wc * 64 + ni * 16 + (lane & 15);
#pragma unroll
      for (int q = 0; q < 4; ++q) {
        long off = (long)(rowb + q) * ldC + col;
        float v = acc[mi][ni][q];
        if (WF32) Cf[off] = v;
        if (WBF == 1) Cb[off] = f2b(v);
        if (WBF == 2) {
          unsigned short h = f2b(v);
          Cb[off] = h;
          Cb2[off] = f2b(v - b2f(h));
        }
      }
    }
  }
}

// ---- GCN MFMA: x = d_m*(sum_k A[m,k]*B[n,k] + d_m*XW[m,n]) + bias[n] -------
// A = adj bf16 (hi[+lo]), B = (d .* XW)^T bf16 (hi[+lo]); SPLIT: 3-product.
template<int SPLIT, int RELU>
__global__ __launch_bounds__(256) void k_mfma_gcn(
    const unsigned short* __restrict__ Ah, const unsigned short* __restrict__ Al,
    const unsigned short* __restrict__ Bh, const unsigned short* __restrict__ Bl,
    const float* __restrict__ dvv, const float* __restrict__ XW,
    const float* __restrict__ bias, float* __restrict__ Cf, int F) {
  __shared__ unsigned short AsH[128 * 32], BsH[128 * 32];
  __shared__ unsigned short AsL[SPLIT ? 128 * 32 : 16], BsL[SPLIT ? 128 * 32 : 16];
  int bz = blockIdx.z;
  const unsigned short* Ahb = Ah + (long)bz * NN * NN;
  const unsigned short* Alb = SPLIT ? Al + (long)bz * NN * NN : nullptr;
  const unsigned short* Bhb = Bh + (long)bz * F * NN;
  const unsigned short* Blb = SPLIT ? Bl + (long)bz * F * NN : nullptr;
  int m0 = blockIdx.y * 128, n0 = blockIdx.x * 128;
  int tid = threadIdx.x, lane = tid & 63, w = tid >> 6;
  int wr = w >> 1, wc = w & 1;
  facc4 acc[4][4];
#pragma unroll
  for (int i = 0; i < 4; ++i)
#pragma unroll
    for (int j = 0; j < 4; ++j)
#pragma unroll
      for (int q = 0; q < 4; ++q) acc[i][j][q] = 0.f;

  int rA0 = w * 16 + (lane >> 2);
  int kslot = lane & 3;

  for (int k0 = 0; k0 < NN; k0 += 32) {
#pragma unroll
    for (int i = 0; i < 2; ++i) {
      int row = i * 64 + rA0;
      int ks = (kslot ^ (row & 3)) << 3;
      int ld = (i * 64 + w * 16) * 32;
      GLOAD16(Ahb + (long)(m0 + row) * NN + k0 + ks, AsH + ld);
      GLOAD16(Bhb + (long)(n0 + row) * NN + k0 + ks, BsH + ld);
      if (SPLIT) {
        GLOAD16(Alb + (long)(m0 + row) * NN + k0 + ks, AsL + ld);
        GLOAD16(Blb + (long)(n0 + row) * NN + k0 + ks, BsL + ld);
      }
    }
    __syncthreads();
    bfrag8 afh[4], bfh[4], afl[4], bfl[4];
#pragma unroll
    for (int mi = 0; mi < 4; ++mi) {
      int row = wr * 64 + mi * 16 + (lane & 15);
      int sl = (((lane >> 4) ^ (row & 3)) << 3);
      afh[mi] = *(const bfrag8*)(AsH + row * 32 + sl);
      if (SPLIT) afl[mi] = *(const bfrag8*)(AsL + row * 32 + sl);
    }
#pragma unroll
    for (int ni = 0; ni < 4; ++ni) {
      int row = wc * 64 + ni * 16 + (lane & 15);
      int sl = (((lane >> 4) ^ (row & 3)) << 3);
      bfh[ni] = *(const bfrag8*)(BsH + row * 32 + sl);
      if (SPLIT) bfl[ni] = *(const bfrag8*)(BsL + row * 32 + sl);
    }
#pragma unroll
    for (int mi = 0; mi < 4; ++mi)
#pragma unroll
      for (int ni = 0; ni < 4; ++ni) {
        acc[mi][ni] = __builtin_amdgcn_mfma_f32_16x16x32_bf16(
            afh[mi], bfh[ni], acc[mi][ni], 0, 0, 0);
        if (SPLIT) {
          acc[mi][ni] = __builtin_amdgcn_mfma_f32_16x16x32_bf16(
              afh[mi], bfl[ni], acc[mi][ni], 0, 0, 0);
          acc[mi][ni] = __builtin_amdgcn_mfma_f32_16x16x32_bf16(
              afl[mi], bfh[ni], acc[mi][ni], 0, 0, 0);
        }
      }
    __syncthreads();
  }
  Cf += (long)bz * NN * F;
#pragma unroll
  for (int mi = 0; mi < 4; ++mi) {
    int rowb = m0 + wr * 64 + mi * 16 + ((lane >> 4) << 2);
#pragma unroll
    for (int ni = 0; ni < 4; ++ni) {
      int col = n0 + wc * 64 + ni * 16 + (lane & 15);
      float bcol = bias[col];
#pragma unroll
      for (int q = 0; q < 4; ++q) {
        float dm = dvv[(bz << 10) + rowb + q];
        float xwv = XW[((long)(bz << 10) + rowb + q) * F + col];
        float v = dm * (acc[mi][ni][q] + dm * xwv) + bcol;
        if (RELU) v = fmaxf(v, 0.f);
        Cf[(long)(rowb + q) * F + col] = v;
      }
    }
  }
}

// ---- split-bf16 3-product NT MFMA Gram + fused C^T write -------------------
__global__ __launch_bounds__(256) void k_mfma_gram(
    const unsigned short* __restrict__ Ah, const unsigned short* __restrict__ Al,
    const unsigned short* __restrict__ Bh, const unsigned short* __restrict__ Bl,
    const float* __restrict__ xx, const float* __restrict__ yy,
    float* __restrict__ Cf, float* __restrict__ Ct) {
  __shared__ unsigned short AsH[128 * 32], AsL[128 * 32];
  __shared__ unsigned short BsH[128 * 32], BsL[128 * 32];
  int bz = blockIdx.z;
  long boff = (long)bz * NN * FIN;
  Ah += boff; Al += boff; Bh += boff; Bl += boff;
  const float* xxb = xx + (bz << 10);
  const float* yyb = yy + (bz << 10);
  int m0 = blockIdx.y * 128, n0 = blockIdx.x * 128;
  int tid = threadIdx.x, lane = tid & 63, w = tid >> 6;
  int wr = w >> 1, wc = w & 1;
  facc4 acc[4][4];
#pragma unroll
  for (int i = 0; i < 4; ++i)
#pragma unroll
    for (int j = 0; j < 4; ++j)
#pragma unroll
      for (int q = 0; q < 4; ++q) acc[i][j][q] = 0.f;

  int rA0 = w * 16 + (lane >> 2);
  int kslot = lane & 3;

  for (int k0 = 0; k0 < FIN; k0 += 32) {
#pragma unroll
    for (int i = 0; i < 2; ++i) {
      int row = i * 64 + rA0;
      int ks = (kslot ^ (row & 3)) << 3;
      long ga = (long)(m0 + row) * FIN + k0 + ks;
      long gb = (long)(n0 + row) * FIN + k0 + ks;
      int ld = (i * 64 + w * 16) * 32;
      GLOAD16(Ah + ga, AsH + ld);
      GLOAD16(Al + ga, AsL + ld);
      GLOAD16(Bh + gb, BsH + ld);
      GLOAD16(Bl + gb, BsL + ld);
    }
    __syncthreads();
    bfrag8 afh[4], afl[4], bfh[4], bfl[4];
#pragma unroll
    for (int mi = 0; mi < 4; ++mi) {
      int row = wr * 64 + mi * 16 + (lane & 15);
      int sl = (((lane >> 4) ^ (row & 3)) << 3);
      afh[mi] = *(const bfrag8*)(AsH + row * 32 + sl);
      afl[mi] = *(const bfrag8*)(AsL + row * 32 + sl);
    }
#pragma unroll
    for (int ni = 0; ni < 4; ++ni) {
      int row = wc * 64 + ni * 16 + (lane & 15);
      int sl = (((lane >> 4) ^ (row & 3)) << 3);
      bfh[ni] = *(const bfrag8*)(BsH + row * 32 + sl);
      bfl[ni] = *(const bfrag8*)(BsL + row * 32 + sl);
    }
#pragma unroll
    for (int mi = 0; mi < 4; ++mi)
#pragma unroll
      for (int ni = 0; ni < 4; ++ni) {
        acc[mi][ni] = __builtin_amdgcn_mfma_f32_16x16x32_bf16(
            afh[mi], bfh[ni], acc[mi][ni], 0, 0, 0);
        acc[mi][ni] = __builtin_amdgcn_mfma_f32_16x16x32_bf16(
            afh[mi], bfl[ni], acc[mi][ni], 0, 0, 0);
        acc[mi][ni] = __builtin_amdgcn_mfma_f32_16x16x32_bf16(
            afl[mi], bfh[ni], acc[mi][ni], 0, 0, 0);
      }
    __syncthreads();
  }
  Cf += (long)bz * NN * NN;
  Ct += (long)bz * NN * NN;
#pragma unroll
  for (int mi = 0; mi < 4; ++mi) {
    int rowb = m0 + wr * 64 + mi * 16 + ((lane >> 4) << 2);
#pragma unroll
    for (int ni = 0; ni < 4; ++ni) {
      int col = n0 + wc * 64 + ni * 16 + (lane & 15);
      float yv = yyb[col];
      float4 tv;
#pragma unroll
      for (int q = 0; q < 4; ++q) {
        float v = xxb[rowb + q] + yv - 2.f * acc[mi][ni][q];
        Cf[(long)(rowb + q) * NN + col] = v;
        ((float*)&tv)[q] = v;
      }
      *(float4*)(Ct + (long)col * NN + rowb) = tv;   // transposed write
    }
  }
}

// ---------------- s0 = cx @ Watt  (per-row dot, HID=128) --------------------
__global__ __launch_bounds__(256) void k_rowdot(const float* __restrict__ X,
                                                const float* __restrict__ w,
                                                float* __restrict__ out) {
  int t = threadIdx.x; int lane = t & 63; int wv = t >> 6;
  int row = blockIdx.x * 4 + wv;
  const float* xr = X + (long)row * HIDN;
  float s = xr[lane] * w[lane] + xr[lane + 64] * w[lane + 64];
  s = wred_sum(s);
  if (lane == 0) out[row] = s;
}

// ---- alpha (4 rows/block) = sigmoid((gcn_norm(adj) @ s0 + batt)^2) ---------
__global__ __launch_bounds__(256) void k_alpha4(const float* __restrict__ adj,
                                                const float* __restrict__ dv,
                                                const float* __restrict__ s0,
                                                const float* __restrict__ batt,
                                                float* __restrict__ alpha) {
  int r0 = blockIdx.x << 2; int b = r0 >> 10; int i0 = r0 & (NN - 1);
  int t = threadIdx.x, lane = t & 63, wv = t >> 6;
  float4 d4 = ((const float4*)(dv + (b << 10)))[t];
  float4 s4 = ((const float4*)(s0 + (b << 10)))[t];
  float w4[4];
  w4[0] = d4.x * s4.x; w4[1] = d4.y * s4.y; w4[2] = d4.z * s4.z; w4[3] = d4.w * s4.w;
  __shared__ float sm[4][4];
#pragma unroll
  for (int r = 0; r < 4; ++r) {
    float4 a4 = ((const float4*)(adj + (long)(r0 + r) * NN))[t];
    float dot = a4.x * w4[0] + a4.y * w4[1] + a4.z * w4[2] + a4.w * w4[3];
    int i = i0 + r;
    if ((i >> 2) == t) dot += w4[i & 3];   // +I diagonal
    dot = wred_sum(dot);
    if (lane == 0) sm[wv][r] = dot;
  }
  __syncthreads();
  if (t < 4) {
    float dot = sm[0][t] + sm[1][t] + sm[2][t] + sm[3][t];
    float tt = dv[r0 + t] * dot + batt[0];
    alpha[r0 + t] = 1.f / (1.f + __expf(-tt * tt));
  }
}

// ---------------- per-batch k-th largest via bitonic sort -------------------
__global__ __launch_bounds__(512) void k_topk(const float* __restrict__ alpha,
                                              float* __restrict__ cut) {
  __shared__ float smv[NN];
  int b = blockIdx.x; int t = threadIdx.x;
  smv[t] = alpha[(b << 10) + t];
  smv[t + 512] = alpha[(b << 10) + t + 512];
  __syncthreads();
  for (int k2 = 2; k2 <= NN; k2 <<= 1) {
    for (int j2 = k2 >> 1; j2 > 0; j2 >>= 1) {
      int i = ((t / j2) * (j2 << 1)) + (t % j2);
      int ixj = i + j2;
      bool up = ((i & k2) == 0);
      float a = smv[i], c = smv[ixj];
      if ((a > c) == up) { smv[i] = c; smv[ixj] = a; }
      __syncthreads();
    }
  }
  if (t == 0) cut[b] = smv[NN - KTOP];
}

// ---- S build (4 rows/block): rmask_i d_i d_j (adj+I) gate_j, row-L1 norm ---
__global__ __launch_bounds__(256) void k_sbuild4(const float* __restrict__ adj,
                                                 const float* __restrict__ dv,
                                                 const float* __restrict__ rm,
                                                 const float* __restrict__ alpha,
                                                 const float* __restrict__ cut,
                                                 float* __restrict__ S) {
  int r0 = blockIdx.x << 2; int b = r0 >> 10; int i0 = r0 & (NN - 1);
  int t = threadIdx.x, lane = t & 63, wv = t >> 6;
  float cb = cut[b];
  float4 d4 = ((const float4*)(dv + (b << 10)))[t];
  float4 al4 = ((const float4*)(alpha + (b << 10)))[t];
  float4 dg;
  dg.x = d4.x * fmaxf(al4.x + 1e-7f - cb, 0.f);
  dg.y = d4.y * fmaxf(al4.y + 1e-7f - cb, 0.f);
  dg.z = d4.z * fmaxf(al4.z + 1e-7f - cb, 0.f);
  dg.w = d4.w * fmaxf(al4.w + 1e-7f - cb, 0.f);
  __shared__ float sm[4][4];
  __shared__ float sinv[4];
  float4 vals[4];
#pragma unroll
  for (int r = 0; r < 4; ++r) {
    float di = dv[r0 + r] * rm[r0 + r];
    float4 a4 = ((const float4*)(adj + (long)(r0 + r) * NN))[t];
    int i = i0 + r;
    if ((i >> 2) == t) ((float*)&a4)[i & 3] += 1.f;
    vals[r].x = di * dg.x * a4.x; vals[r].y = di * dg.y * a4.y;
    vals[r].z = di * dg.z * a4.z; vals[r].w = di * dg.w * a4.w;
    float s = (fabsf(vals[r].x) + fabsf(vals[r].y)) +
              (fabsf(vals[r].z) + fabsf(vals[r].w));
    s = wred_sum(s);
    if (lane == 0) sm[wv][r] = s;
  }
  __syncthreads();
  if (t < 4) sinv[t] = 1.f / fmaxf(sm[0][t] + sm[1][t] + sm[2][t] + sm[3][t], 1e-12f);
  __syncthreads();
#pragma unroll
  for (int r = 0; r < 4; ++r) {
    float inv = sinv[r];
    float4 o; o.x = vals[r].x * inv; o.y = vals[r].y * inv;
    o.z = vals[r].z * inv; o.w = vals[r].w * inv;
    ((float4*)(S + (long)(r0 + r) * NN))[t] = o;
  }
}

// ---------------- K-split fp32 GEMM (TA=0,TB=0), partials out ---------------
template<int GCN>
__global__ __launch_bounds__(256) void k_gemm_ks(
    const float* __restrict__ A, const float* __restrict__ Bm, float* __restrict__ P,
    int M, int Nn, int K, int KS, long sA, long sB,
    const float* __restrict__ dv) {
  __shared__ float As[8][132];
  __shared__ float Bs[8][132];
  int z = blockIdx.z;
  int b = z / KS, ks = z % KS;
  int KC = K / KS;
  A += (long)b * sA; Bm += (long)b * sB;
  const float* dvb = GCN ? (dv + (long)b * NN) : nullptr;
  int m0 = blockIdx.y * 128, n0 = blockIdx.x * 128;
  int tid = threadIdx.x;
  int tx = tid & 15, ty = tid >> 4;
  float acc[8][8];
#pragma unroll
  for (int i = 0; i < 8; i++)
#pragma unroll
    for (int j = 0; j < 8; j++) acc[i][j] = 0.f;

  float drow = 0.f;
  if (GCN) drow = dvb[m0 + (tid >> 1)];

  for (int k0 = ks * KC; k0 < ks * KC + KC; k0 += 8) {
    {
      int r = tid >> 1, c4 = (tid & 1) * 4;
      float4 av = *(const float4*)(A + (long)(m0 + r) * K + k0 + c4);
      float a4[4] = {av.x, av.y, av.z, av.w};
      if (GCN) {
#pragma unroll
        for (int q = 0; q < 4; ++q) {
          int gj = k0 + c4 + q;
          float val = a4[q] + ((m0 + r) == gj ? 1.f : 0.f);
          a4[q] = drow * dvb[gj] * val;
        }
      }
      As[c4 + 0][r] = a4[0]; As[c4 + 1][r] = a4[1];
      As[c4 + 2][r] = a4[2]; As[c4 + 3][r] = a4[3];
    }
    {
      int kr = tid >> 5, c4 = (tid & 31) * 4;
      float4 bv = *(const float4*)(Bm + (long)(k0 + kr) * Nn + n0 + c4);
      *(float4*)&Bs[kr][c4] = bv;
    }
    __syncthreads();
#pragma unroll
    for (int k = 0; k < 8; ++k) {
      float av[8], bv[8];
      *(float4*)&av[0] = *(const float4*)&As[k][ty * 8];
      *(float4*)&av[4] = *(const float4*)&As[k][ty * 8 + 4];
      *(float4*)&bv[0] = *(const float4*)&Bs[k][tx * 8];
      *(float4*)&bv[4] = *(const float4*)&Bs[k][tx * 8 + 4];
#pragma unroll
      for (int i = 0; i < 8; i++)
#pragma unroll
        for (int j = 0; j < 8; j++)
          acc[i][j] = fmaf(av[i], bv[j], acc[i][j]);
    }
    __syncthreads();
  }
  float* Pz = P + (long)z * M * Nn;
#pragma unroll
  for (int i = 0; i < 8; ++i) {
    int m = m0 + ty * 8 + i;
    float* prow = Pz + (long)m * Nn + n0 + tx * 8;
    *(float4*)&prow[0] = *(float4*)&acc[i][0];
    *(float4*)&prow[4] = *(float4*)&acc[i][4];
  }
}

// ---------------- reduce K-split partials (+bias, +relu) --------------------
template<int RELU, int BIAS>
__global__ __launch_bounds__(256) void k_red_bias(
    const float* __restrict__ P, const float* __restrict__ bias,
    float* __restrict__ out, int Nn, int KS, long chunk) {
  long u = ((long)blockIdx.x * 256 + threadIdx.x) * 4;
  long b = u / chunk; long rem = u % chunk;
  const float* p = P + b * KS * chunk + rem;
  float4 s = *(const float4*)p;
  for (int k = 1; k < KS; ++k) {
    float4 q = *(const float4*)(p + (long)k * chunk);
    s.x += q.x; s.y += q.y; s.z += q.z; s.w += q.w;
  }
  if (BIAS) {
    int n = (int)(rem % Nn);
    s.x += bias[n]; s.y += bias[n + 1]; s.z += bias[n + 2]; s.w += bias[n + 3];
  }
  if (RELU) {
    s.x = fmaxf(s.x, 0.f); s.y = fmaxf(s.y, 0.f);
    s.z = fmaxf(s.z, 0.f); s.w = fmaxf(s.w, 0.f);
  }
  *(float4*)(out + u) = s;
}

// ---------------- column mean over nodes ------------------------------------
__global__ __launch_bounds__(256) void k_colmean(const float* __restrict__ X, int Fd,
                                                 float* __restrict__ out) {
  int nb = Fd >> 6;
  int b = blockIdx.x / nb; int f0 = (blockIdx.x % nb) << 6;
  int t = threadIdx.x;
  int f = f0 + (t & 63); int rc = t >> 6;
  const float* xb = X + (long)b * NN * Fd;
  float s = 0.f;
  for (int i = rc * 256; i < rc * 256 + 256; ++i) s += xb[(long)i * Fd + f];
  __shared__ float sm[256];
  sm[t] = s; __syncthreads();
  if (t < 64) out[b * Fd + f] = (sm[t] + sm[t + 64] + sm[t + 128] + sm[t + 192]) * (1.f / NN);
}

// ---------------- squared row norms -----------------------------------------
__global__ __launch_bounds__(256) void k_sqnorm(const float* __restrict__ X, int Fd,
                                                float* __restrict__ out) {
  int t = threadIdx.x; int lane = t & 63; int wv = t >> 6;
  int row = blockIdx.x * 4 + wv;
  const float* xr = X + (long)row * Fd;
  float s = 0.f;
  for (int f = lane; f < Fd; f += 64) { float v = xr[f]; s = fmaf(v, v, s); }
  s = wred_sum(s);
  if (lane == 0) out[row] = s;
}

// ---------------- persistent Sinkhorn: all 40 passes + loss -----------------
static __device__ __forceinline__ void gridbar(int* cnt, int* gen, int g) {
  __syncthreads();
  if (threadIdx.x == 0) {
    __threadfence();
    int prev = __hip_atomic_fetch_add(cnt, 1, __ATOMIC_ACQ_REL,
                                      __HIP_MEMORY_SCOPE_AGENT);
    if (prev == SNB - 1) {
      __hip_atomic_store(cnt, 0, __ATOMIC_RELAXED, __HIP_MEMORY_SCOPE_AGENT);
      __hip_atomic_fetch_add(gen, 1, __ATOMIC_RELEASE, __HIP_MEMORY_SCOPE_AGENT);
    } else {
      while (__hip_atomic_load(gen, __ATOMIC_ACQUIRE,
                               __HIP_MEMORY_SCOPE_AGENT) <= g) {
        __builtin_amdgcn_s_sleep(8);
      }
    }
  }
  __syncthreads();
}

template<int LOSS>
static __device__ __forceinline__ void sink_pass_w(
    const float* __restrict__ Mb, const float* __restrict__ vin,
    float* __restrict__ uout, int wrow0, int b, int lane, float* lossacc) {
  const float4* vb = (const float4*)(vin + (b << 10));
  float4 v0 = vb[lane], v1 = vb[lane + 64], v2 = vb[lane + 128], v3 = vb[lane + 192];
#pragma unroll
  for (int r = 0; r < 4; ++r) {
    int row = wrow0 + r;
    const float4* cr = (const float4*)(Mb + (long)row * NN);
    float4 c0 = cr[lane], c1 = cr[lane + 64], c2 = cr[lane + 128], c3 = cr[lane + 192];
    float4 a0, a1, a2, a3;
    a0.x = (v0.x - c0.x) * INV_EPS; a0.y = (v0.y - c0.y) * INV_EPS;
    a0.z = (v0.z - c0.z) * INV_EPS; a0.w = (v0.w - c0.w) * INV_EPS;
    a1.x = (v1.x - c1.x) * INV_EPS; a1.y = (v1.y - c1.y) * INV_EPS;
    a1.z = (v1.z - c1.z) * INV_EPS; a1.w = (v1.w - c1.w) * INV_EPS;
    a2.x = (v2.x - c2.x) * INV_EPS; a2.y = (v2.y - c2.y) * INV_EPS;
    a2.z = (v2.z - c2.z) * INV_EPS; a2.w = (v2.w - c2.w) * INV_EPS;
    a3.x = (v3.x - c3.x) * INV_EPS; a3.y = (v3.y - c3.y) * INV_EPS;
    a3.z = (v3.z - c3.z) * INV_EPS; a3.w = (v3.w - c3.w) * INV_EPS;
    float lm = fmaxf(fmaxf(max4(a0), max4(a1)), fmaxf(max4(a2), max4(a3)));
    lm = wred_max(lm);
    float ls, ld = 0.f;
    if (LOSS) {
      float e;
      ls = 0.f;
      e = __expf(a0.x - lm); ls += e; ld = fmaf(e, c0.x, ld);
      e = __expf(a0.y - lm); ls += e; ld = fmaf(e, c0.y, ld);
      e = __expf(a0.z - lm); ls += e; ld = fmaf(e, c0.z, ld);
      e = __expf(a0.w - lm); ls += e; ld = fmaf(e, c0.w, ld);
      e = __expf(a1.x - lm); ls += e; ld = fmaf(e, c1.x, ld);
      e = __expf(a1.y - lm); ls += e; ld = fmaf(e, c1.y, ld);
      e = __expf(a1.z - lm); ls += e; ld = fmaf(e, c1.z, ld);
      e = __expf(a1.w - lm); ls += e; ld = fmaf(e, c1.w, ld);
      e = __expf(a2.x - lm); ls += e; ld = fmaf(e, c2.x, ld);
      e = __expf(a2.y - lm); ls += e; ld = fmaf(e, c2.y, ld);
      e = __expf(a2.z - lm); ls += e; ld = fmaf(e, c2.z, ld);
      e = __expf(a2.w - lm); ls += e; ld = fmaf(e, c2.w, ld);
      e = __expf(a3.x - lm); ls += e; ld = fmaf(e, c3.x, ld);
      e = __expf(a3.y - lm); ls += e; ld = fmaf(e, c3.y, ld);
      e = __expf(a3.z - lm); ls += e; ld = fmaf(e, c3.z, ld);
      e = __expf(a3.w - lm); ls += e; ld = fmaf(e, c3.w, ld);
    } else {
      ls = esum4(a0, lm) + esum4(a1, lm) + esum4(a2, lm) + esum4(a3, lm);
    }
    ls = wred_sum(ls);
    if (LOSS) ld = wred_sum(ld);
    if (lane == 0) {
      uout[row] = EPS_S * (LOG_MU - (lm + __logf(ls)));
      if (LOSS) *lossacc += (ld / ls) * (1.0f / 1024.0f);
    }
  }
}

__global__ __launch_bounds__(512, 2) void k_sink_all(
    const float* __restrict__ Cm, const float* __restrict__ Ct,
    float* __restrict__ uv, float* __restrict__ vv,
    float* __restrict__ part, float* __restrict__ oloss, int* __restrict__ bar) {
  int bid = blockIdx.x, t = threadIdx.x, lane = t & 63, wv = t >> 6;
  int wrow0 = bid * 32 + wv * 4;      // 256 blocks * 8 waves * 4 rows = 8192
  int b = wrow0 >> 10;
  int* cnt = bar; int* gen = bar + 1;
  int g = 0;
  float lossacc = 0.f;
  for (int it = 0; it < NITER; ++it) {
    sink_pass_w<0>(Cm, vv, uv, wrow0, b, lane, nullptr);
    gridbar(cnt, gen, g); ++g;
    if (it < NITER - 1) {
      sink_pass_w<0>(Ct, uv, vv, wrow0, b, lane, nullptr);
    } else {
      sink_pass_w<1>(Ct, uv, vv, wrow0, b, lane, &lossacc);
    }
    gridbar(cnt, gen, g); ++g;
  }
  __shared__ float lsm[8];
  if (lane == 0) lsm[wv] = lossacc;
  __syncthreads();
  if (t == 0) {
    float s = 0.f;
#pragma unroll
    for (int i = 0; i < 8; ++i) s += lsm[i];
    part[bid] = s;
  }
  gridbar(cnt, gen, g);
  if (bid == 0) {
    float s = (t < SNB) ? part[t] : 0.f;
    s = wred_sum(s);
    __shared__ float sm2[8];
    if (lane == 0) sm2[wv] = s;
    __syncthreads();
    if (t == 0) {
      float tot = 0.f;
#pragma unroll
      for (int i = 0; i < 8; ++i) tot += sm2[i];
      oloss[0] = tot;
    }
  }
}

extern "C" void kernel_launch(void* const* d_in, const int* in_sizes, int n_in,
                              void* d_out, int out_size, void* d_ws, size_t ws_size,
                              hipStream_t stream) {
  const float* x    = (const float*)d_in[0];
  const float* adj  = (const float*)d_in[1];
  const float* W1   = (const float*)d_in[3];
  const float* b1   = (const float*)d_in[4];
  const float* Watt = (const float*)d_in[5];
  const float* batt = (const float*)d_in[6];
  const float* W2   = (const float*)d_in[7];
  const float* b2   = (const float*)d_in[8];

  float* out = (float*)d_out;
  float* xs0   = out;                    // [8,128]
  float* xs1   = out + 1024;             // [8,256]
  float* oadj0 = out + 3072;             // [8,1024,1024]
  float* oadj1 = oadj0 + 8388608;
  float* oadj2 = oadj1 + 8388608;        // adj_bf scratch until adj2 written
  float* oS0   = oadj2 + 8388608;
  float* oS1   = oS0 + 8388608;
  float* oloss = oS1 + 8388608;          // [1]

  float* ws   = (float*)d_ws;
  float* wXW  = ws;                       // 2,097,152 (XW1 then XW2)
  float* wCXA = wXW + 2097152;            // 1,048,576 (x1, later emb2)
  float* wCXB = wCXA + 1048576;           // 1,048,576 (emb1)
  float* wR   = wCXB + 1048576;           // 8,388,608 (tmp_bf | P | Cmat)
  float* wX2  = wR + 8388608;             // 2,097,152 (x2)
  float* wStf = wX2 + 2097152;            // 4,194,304 (x_bf/St/Bg2/x-splits)
  float* wCxtf= wStf + 4194304;           // 524,288   (Bg1 / cxt)
  float* wCt  = wCxtf + 524288;           // 8,388,608 (a2h+a2l, then C^T)
  float* smb  = wCt + 8388608;

  unsigned short* tmp_bf = (unsigned short*)wR;                 // 16.7MB half
  unsigned short* a2h    = (unsigned short*)wCt;                // 8,388,608 sh
  unsigned short* a2l    = a2h + 8388608;                       // 8,388,608 sh
  unsigned short* adj_bf = (unsigned short*)oadj2;
  unsigned short* St     = (unsigned short*)wStf;
  unsigned short* cxt    = (unsigned short*)wCxtf;
  unsigned short* x_bf   = (unsigned short*)wStf;               // pre-coarsen
  unsigned short* Bg1    = (unsigned short*)wCxtf;
  unsigned short* Bg2h   = (unsigned short*)wStf;               // post-adj2
  unsigned short* Bg2l   = (unsigned short*)(wStf + 2097152);
  unsigned short* xh  = (unsigned short*)wStf;                  // sinkhorn phase
  unsigned short* xl  = xh + 2097152;
  unsigned short* x2h = xh + 4194304;
  unsigned short* x2l = xh + 6291456;
  float* Cmat = wR;
  float* d0 = smb;            float* rm0 = smb + 8192;
  float* d1 = smb + 16384;    float* rm1 = smb + 24576;
  float* d2 = smb + 32768;    float* rm2 = smb + 40960;
  float* s0v = smb + 49152;   float* alp = smb + 57344;
  float* xxv = smb + 65536;   float* yyv = smb + 73728;
  float* uv  = smb + 81920;   float* vv  = smb + 90112;   // contiguous
  float* cutv = smb + 98304;  float* part = smb + 98368;  // 256
  unsigned short* W1t = (unsigned short*)(smb + 98624);    // 32768 shorts
  int* bar = (int*)(smb + 115008);                         // 2 ints

  // rowstats on adj + fused bf16 copy (into oadj2 region) + fp32 copy (oadj0)
  k_rowstats4<1, 1><<<2048, 256, 0, stream>>>(adj, d0, rm0, adj_bf, oadj0);

  // ---- GCN1 (MFMA): x1 = relu(d*(adj_bf @ (d.*XW1) + d*XW1_diag) + b1) ----
  k_f2b<<<2048, 256, 0, stream>>>(x, x_bf);
  k_w1t<<<128, 256, 0, stream>>>(W1, W1t);
  k_mfma_nt<1, 0><<<dim3(1, 64, 1), 256, 0, stream>>>(x_bf, W1t, wXW, nullptr,
      nullptr, 256, 256, 256, 128, 0L, 0L, 0L);
  k_stc<0><<<dim3(16, 2, 8), 256, 0, stream>>>(wXW, d0, Bg1, nullptr, HIDN);
  k_mfma_gcn<0, 1><<<dim3(1, 8, 8), 256, 0, stream>>>(adj_bf, nullptr, Bg1,
      nullptr, d0, wXW, b1, wCXA, HIDN);
  k_colmean<<<16, 256, 0, stream>>>(wCXA, HIDN, xs0);

  // ---- coarsen layer 1 ----
  k_rowdot<<<2048, 256, 0, stream>>>(wCXA, Watt, s0v);
  k_alpha4<<<2048, 256, 0, stream>>>(adj, d0, s0v, batt, alp);
  k_topk<<<8, 512, 0, stream>>>(alp, cutv);
  k_sbuild4<<<2048, 256, 0, stream>>>(adj, d0, rm0, alp, cutv, oS0);
  k_transp<<<dim3(16, 16, 8), 256, 0, stream>>>(oS0, St, 1024, 1024);
  k_transp<<<dim3(2, 16, 8), 256, 0, stream>>>(wCXA, cxt, 1024, 128);
  k_mfma_nt<1, 0><<<dim3(1, 8, 8), 256, 0, stream>>>(St, cxt, wCXB, nullptr,
      nullptr, 1024, 1024, 1024, 128, 1048576L, 131072L, 131072L);
  k_mfma_nt<0, 1><<<dim3(8, 8, 8), 256, 0, stream>>>(St, adj_bf, nullptr, tmp_bf,
      nullptr, 1024, 1024, 1024, 1024, 1048576L, 1048576L, 1048576L);
  k_mfma_nt<1, 1><<<dim3(8, 8, 8), 256, 0, stream>>>(tmp_bf, St, oadj1, adj_bf,
      nullptr, 1024, 1024, 1024, 1024, 1048576L, 1048576L, 1048576L);
  k_rowstats4<0, 0><<<2048, 256, 0, stream>>>(oadj1, d1, rm1, nullptr, nullptr);

  // ---- coarsen layer 2 ----
  k_rowdot<<<2048, 256, 0, stream>>>(wCXB, Watt, s0v);
  k_alpha4<<<2048, 256, 0, stream>>>(oadj1, d1, s0v, batt, alp);
  k_topk<<<8, 512, 0, stream>>>(alp, cutv);
  k_sbuild4<<<2048, 256, 0, stream>>>(oadj1, d1, rm1, alp, cutv, oS1);
  k_transp<<<dim3(16, 16, 8), 256, 0, stream>>>(oS1, St, 1024, 1024);
  k_transp<<<dim3(2, 16, 8), 256, 0, stream>>>(wCXB, cxt, 1024, 128);
  k_mfma_nt<1, 0><<<dim3(1, 8, 8), 256, 0, stream>>>(St, cxt, wCXA, nullptr,
      nullptr, 1024, 1024, 1024, 128, 1048576L, 131072L, 131072L);
  k_mfma_nt<0, 1><<<dim3(8, 8, 8), 256, 0, stream>>>(St, adj_bf, nullptr, tmp_bf,
      nullptr, 1024, 1024, 1024, 1024, 1048576L, 1048576L, 1048576L);
  // adj2 -> fp32 output + hi/lo bf16 pair (in wCt region) for split final GCN
  k_mfma_nt<1, 2><<<dim3(8, 8, 8), 256, 0, stream>>>(tmp_bf, St, oadj2, a2h,
      a2l, 1024, 1024, 1024, 1024, 1048576L, 1048576L, 1048576L);
  k_rowstats4<0, 0><<<2048, 256, 0, stream>>>(oadj2, d2, rm2, nullptr, nullptr);

  // ---- final GCN (split-bf16 MFMA): x2 = d*(A2@(d.*XW2) + d*XW2_diag) + b2 --
  k_gemm_ks<0><<<dim3(2, 64, 2), 256, 0, stream>>>(wCXA, W2, wR, 8192, FIN, HIDN,
      2, 0L, 0L, nullptr);   // P partials in wR first half (tmp_bf dead)
  k_red_bias<0, 0><<<2048, 256, 0, stream>>>(wR, nullptr, wXW, FIN, 2, 2097152L);
  k_stc<1><<<dim3(16, 4, 8), 256, 0, stream>>>(wXW, d2, Bg2h, Bg2l, FIN);
  k_mfma_gcn<1, 0><<<dim3(2, 8, 8), 256, 0, stream>>>(a2h, a2l, Bg2h, Bg2l,
      d2, wXW, b2, wX2, FIN);
  k_colmean<<<32, 256, 0, stream>>>(wX2, FIN, xs1);

  // ---- Sinkhorn: C via split-bf16 MFMA Gram (+fused C^T), persistent solve --
  k_sqnorm<<<2048, 256, 0, stream>>>(x, FIN, xxv);
  k_sqnorm<<<2048, 256, 0, stream>>>(wX2, FIN, yyv);
  k_split2<<<2048, 256, 0, stream>>>(x, xh, xl);
  k_split2<<<2048, 256, 0, stream>>>(wX2, x2h, x2l);
  k_mfma_gram<<<dim3(8, 8, 8), 256, 0, stream>>>(xh, xl, x2h, x2l, xxv, yyv,
      Cmat, wCt);
  hipMemsetAsync(uv, 0, (size_t)2 * 8192 * 4, stream);
  hipMemsetAsync(bar, 0, 8, stream);
  k_sink_all<<<SNB, 512, 0, stream>>>(Cmat, wCt, uv, vv, part, oloss, bar);
}

// Round 7
// 1339.767 us; speedup vs baseline: 1.2567x; 1.2567x over previous
//
#include <hip/hip_runtime.h>
#include <math.h>

// Problem constants (fixed by the reference)
#define BN   8
#define NN   1024
#define FIN  256
#define HIDN 128
#define KTOP 513          // int(1024*0.5)+1
#define NITER 20          // opt_epochs in setup_inputs
#define EPS_S 0.01f
#define INV_EPS 100.0f
#define LOG_MU (-6.9314718055994531f)   // -log(1024)
#define SNB 256           // blocks in persistent sinkhorn kernel

typedef __attribute__((ext_vector_type(8))) short bfrag8;   // 8 bf16 (4 VGPR)
typedef __attribute__((ext_vector_type(4))) float facc4;    // MFMA accumulator

#define GLOAD16(g, l) __builtin_amdgcn_global_load_lds( \
    (const __attribute__((address_space(1))) unsigned int*)(g), \
    (__attribute__((address_space(3))) unsigned int*)(l), 16, 0, 0)

static __device__ __forceinline__ float wred_sum(float s) {
#pragma unroll
  for (int o = 32; o > 0; o >>= 1) s += __shfl_xor(s, o);
  return s;
}
static __device__ __forceinline__ unsigned short f2b(float f) {
  unsigned int u = __float_as_uint(f);
  u += 0x7fff + ((u >> 16) & 1);      // RNE
  return (unsigned short)(u >> 16);
}
static __device__ __forceinline__ float b2f(unsigned short h) {
  return __uint_as_float((unsigned int)h << 16);
}

// ---- rowstats (4 rows/block): d = rsqrt(max(rowsum+1,1)), rmask ------------
template<int WRBF, int WCOPY>
__global__ __launch_bounds__(256) void k_rowstats4(const float* __restrict__ adj,
                                                   float* __restrict__ dv,
                                                   float* __restrict__ rm,
                                                   unsigned short* __restrict__ abf,
                                                   float* __restrict__ ocopy) {
  int r0 = blockIdx.x << 2;
  int t = threadIdx.x, lane = t & 63, wv = t >> 6;
  __shared__ float sm[4][4];
#pragma unroll
  for (int r = 0; r < 4; ++r) {
    float4 v = ((const float4*)(adj + (long)(r0 + r) * NN))[t];
    if (WRBF) {
      ushort4 h; h.x = f2b(v.x); h.y = f2b(v.y); h.z = f2b(v.z); h.w = f2b(v.w);
      *(ushort4*)(abf + (long)(r0 + r) * NN + t * 4) = h;
    }
    if (WCOPY) ((float4*)(ocopy + (long)(r0 + r) * NN))[t] = v;
    float s = (v.x + v.y) + (v.z + v.w);
    s = wred_sum(s);
    if (lane == 0) sm[wv][r] = s;
  }
  __syncthreads();
  if (t < 4) {
    float tot = sm[0][t] + sm[1][t] + sm[2][t] + sm[3][t];
    dv[r0 + t] = rsqrtf(fmaxf(tot + 1.0f, 1.0f));
    rm[r0 + t] = tot > 0.0f ? 1.0f : 0.0f;
  }
}

// ---------------- fp32 -> bf16 elementwise ----------------------------------
__global__ __launch_bounds__(256) void k_f2b(const float* __restrict__ X,
                                             unsigned short* __restrict__ Y) {
  long i = ((long)blockIdx.x * 256 + threadIdx.x) * 4;
  float4 v = *(const float4*)(X + i);
  Y[i] = f2b(v.x); Y[i + 1] = f2b(v.y); Y[i + 2] = f2b(v.z); Y[i + 3] = f2b(v.w);
}

// ---- W1 [256][128] fp32 -> W1t [128][256] bf16 -----------------------------
__global__ __launch_bounds__(256) void k_w1t(const float* __restrict__ W,
                                             unsigned short* __restrict__ Wt) {
  int idx = blockIdx.x * 256 + threadIdx.x;   // 32768
  int n = idx >> 8, k = idx & 255;
  Wt[idx] = f2b(W[k * HIDN + n]);
}

// ---- fp32 X -> bf16 hi + bf16 lo (split for 3-product MFMA) ---------------
__global__ __launch_bounds__(256) void k_split2(const float* __restrict__ X,
                                                unsigned short* __restrict__ Xh,
                                                unsigned short* __restrict__ Xl) {
  long i = ((long)blockIdx.x * 256 + threadIdx.x) * 4;
  float4 v = *(const float4*)(X + i);
  ushort4 h, l;
  h.x = f2b(v.x); l.x = f2b(v.x - b2f(h.x));
  h.y = f2b(v.y); l.y = f2b(v.y - b2f(h.y));
  h.z = f2b(v.z); l.z = f2b(v.z - b2f(h.z));
  h.w = f2b(v.w); l.w = f2b(v.w - b2f(h.w));
  *(ushort4*)(Xh + i) = h;
  *(ushort4*)(Xl + i) = l;
}

// ---------------- fp32 [R][C] -> bf16 [C][R] transpose ----------------------
__global__ __launch_bounds__(256) void k_transp(const float* __restrict__ X,
                                                unsigned short* __restrict__ Xt,
                                                int R, int C) {
  __shared__ float tile[64][65];
  long bb = blockIdx.z;
  const float* Xb = X + bb * (long)R * C;
  unsigned short* Xtb = Xt + bb * (long)R * C;
  int r0 = blockIdx.y * 64, c0 = blockIdx.x * 64;
  int t = threadIdx.x;
  int tr = t >> 4, tc4 = (t & 15) * 4;
#pragma unroll
  for (int p = 0; p < 4; ++p) {
    float4 v = *(const float4*)(Xb + (long)(r0 + tr + p * 16) * C + c0 + tc4);
    tile[tr + p * 16][tc4 + 0] = v.x; tile[tr + p * 16][tc4 + 1] = v.y;
    tile[tr + p * 16][tc4 + 2] = v.z; tile[tr + p * 16][tc4 + 3] = v.w;
  }
  __syncthreads();
  int jj = t >> 2, i0 = (t & 3) * 16;
  unsigned short* orow = Xtb + (long)(c0 + jj) * R + r0 + i0;
#pragma unroll
  for (int q = 0; q < 16; ++q) orow[q] = f2b(tile[i0 + q][jj]);
}

// ---- scale-transpose-cast: Bg[b][n][j] = bf16(d[b*1024+j]*XW[b][j][n]) -----
template<int SPLIT>
__global__ __launch_bounds__(256) void k_stc(const float* __restrict__ XW,
                                             const float* __restrict__ dvv,
                                             unsigned short* __restrict__ Bh,
                                             unsigned short* __restrict__ Bl,
                                             int F) {
  __shared__ float tile[64][65];
  __shared__ float dl[64];
  int bz = blockIdx.z;
  const float* Xb = XW + (long)bz * NN * F;
  int j0 = blockIdx.x * 64;   // node dim
  int n0 = blockIdx.y * 64;   // feature dim
  int t = threadIdx.x;
  int tr = t >> 4, tc4 = (t & 15) * 4;
#pragma unroll
  for (int p = 0; p < 4; ++p) {
    float4 v = *(const float4*)(Xb + (long)(j0 + tr + p * 16) * F + n0 + tc4);
    tile[tr + p * 16][tc4 + 0] = v.x; tile[tr + p * 16][tc4 + 1] = v.y;
    tile[tr + p * 16][tc4 + 2] = v.z; tile[tr + p * 16][tc4 + 3] = v.w;
  }
  if (t < 64) dl[t] = dvv[(bz << 10) + j0 + t];
  __syncthreads();
  int nn = t >> 2, i0 = (t & 3) * 16;
  long obase = ((long)bz * F + n0 + nn) * NN + j0 + i0;
#pragma unroll
  for (int q = 0; q < 16; ++q) {
    float v = tile[i0 + q][nn] * dl[i0 + q];
    unsigned short h = f2b(v);
    Bh[obase + q] = h;
    if (SPLIT) Bl[obase + q] = f2b(v - b2f(h));
  }
}

// ---------------- bf16 NT MFMA GEMM: C[m,n] = sum_k A[m,k]*B[n,k] -----------
template<int WF32, int WBF>
__global__ __launch_bounds__(256) void k_mfma_nt(
    const unsigned short* __restrict__ A, const unsigned short* __restrict__ B,
    float* __restrict__ Cf, unsigned short* __restrict__ Cb,
    unsigned short* __restrict__ Cb2,
    int K, int ldA, int ldB, int ldC, long sA, long sB, long sC) {
  __shared__ unsigned short As[128 * 32];
  __shared__ unsigned short Bs[128 * 32];
  int bz = blockIdx.z;
  A += bz * sA; B += bz * sB;
  int m0 = blockIdx.y * 128, n0 = blockIdx.x * 128;
  int tid = threadIdx.x, lane = tid & 63, w = tid >> 6;
  int wr = w >> 1, wc = w & 1;
  facc4 acc[4][4];
#pragma unroll
  for (int i = 0; i < 4; ++i)
#pragma unroll
    for (int j = 0; j < 4; ++j)
#pragma unroll
      for (int q = 0; q < 4; ++q) acc[i][j][q] = 0.f;

  int rA0 = w * 16 + (lane >> 2);
  int kslot = lane & 3;

  for (int k0 = 0; k0 < K; k0 += 32) {
#pragma unroll
    for (int i = 0; i < 2; ++i) {
      int row = i * 64 + rA0;
      int ks = (kslot ^ (row & 3)) << 3;   // pre-swizzled global source
      GLOAD16(A + (long)(m0 + row) * ldA + k0 + ks, As + (i * 64 + w * 16) * 32);
      GLOAD16(B + (long)(n0 + row) * ldB + k0 + ks, Bs + (i * 64 + w * 16) * 32);
    }
    __syncthreads();
    bfrag8 af[4], bfr[4];
#pragma unroll
    for (int mi = 0; mi < 4; ++mi) {
      int row = wr * 64 + mi * 16 + (lane & 15);
      int sl = (((lane >> 4) ^ (row & 3)) << 3);   // swizzled read
      af[mi] = *(const bfrag8*)(As + row * 32 + sl);
    }
#pragma unroll
    for (int ni = 0; ni < 4; ++ni) {
      int row = wc * 64 + ni * 16 + (lane & 15);
      int sl = (((lane >> 4) ^ (row & 3)) << 3);
      bfr[ni] = *(const bfrag8*)(Bs + row * 32 + sl);
    }
#pragma unroll
    for (int mi = 0; mi < 4; ++mi)
#pragma unroll
      for (int ni = 0; ni < 4; ++ni)
        acc[mi][ni] = __builtin_amdgcn_mfma_f32_16x16x32_bf16(
            af[mi], bfr[ni], acc[mi][ni], 0, 0, 0);
    __syncthreads();
  }
  if (WF32) Cf += bz * sC;
  if (WBF) Cb += bz * sC;
  if (WBF == 2) Cb2 += bz * sC;
#pragma unroll
  for (int mi = 0; mi < 4; ++mi) {
    int rowb = m0 + wr * 64 + mi * 16 + ((lane >> 4) << 2);
#pragma unroll
    for (int ni = 0; ni < 4; ++ni) {
      int col = n0 + wc * 64 + ni * 16 + (lane & 15);
#pragma unroll
      for (int q = 0; q < 4; ++q) {
        long off = (long)(rowb + q) * ldC + col;
        float v = acc[mi][ni][q];
        if (WF32) Cf[off] = v;
        if (WBF == 1) Cb[off] = f2b(v);
        if (WBF == 2) {
          unsigned short h = f2b(v);
          Cb[off] = h;
          Cb2[off] = f2b(v - b2f(h));
        }
      }
    }
  }
}

// ---- GCN MFMA: x = d_m*(sum_k A[m,k]*B[n,k] + d_m*XW[m,n]) + bias[n] -------
template<int SPLIT, int RELU>
__global__ __launch_bounds__(256) void k_mfma_gcn(
    const unsigned short* __restrict__ Ah, const unsigned short* __restrict__ Al,
    const unsigned short* __restrict__ Bh, const unsigned short* __restrict__ Bl,
    const float* __restrict__ dvv, const float* __restrict__ XW,
    const float* __restrict__ bias, float* __restrict__ Cf, int F) {
  __shared__ unsigned short AsH[128 * 32], BsH[128 * 32];
  __shared__ unsigned short AsL[SPLIT ? 128 * 32 : 16], BsL[SPLIT ? 128 * 32 : 16];
  int bz = blockIdx.z;
  const unsigned short* Ahb = Ah + (long)bz * NN * NN;
  const unsigned short* Alb = SPLIT ? Al + (long)bz * NN * NN : nullptr;
  const unsigned short* Bhb = Bh + (long)bz * F * NN;
  const unsigned short* Blb = SPLIT ? Bl + (long)bz * F * NN : nullptr;
  int m0 = blockIdx.y * 128, n0 = blockIdx.x * 128;
  int tid = threadIdx.x, lane = tid & 63, w = tid >> 6;
  int wr = w >> 1, wc = w & 1;
  facc4 acc[4][4];
#pragma unroll
  for (int i = 0; i < 4; ++i)
#pragma unroll
    for (int j = 0; j < 4; ++j)
#pragma unroll
      for (int q = 0; q < 4; ++q) acc[i][j][q] = 0.f;

  int rA0 = w * 16 + (lane >> 2);
  int kslot = lane & 3;

  for (int k0 = 0; k0 < NN; k0 += 32) {
#pragma unroll
    for (int i = 0; i < 2; ++i) {
      int row = i * 64 + rA0;
      int ks = (kslot ^ (row & 3)) << 3;
      int ld = (i * 64 + w * 16) * 32;
      GLOAD16(Ahb + (long)(m0 + row) * NN + k0 + ks, AsH + ld);
      GLOAD16(Bhb + (long)(n0 + row) * NN + k0 + ks, BsH + ld);
      if (SPLIT) {
        GLOAD16(Alb + (long)(m0 + row) * NN + k0 + ks, AsL + ld);
        GLOAD16(Blb + (long)(n0 + row) * NN + k0 + ks, BsL + ld);
      }
    }
    __syncthreads();
    bfrag8 afh[4], bfh[4], afl[4], bfl[4];
#pragma unroll
    for (int mi = 0; mi < 4; ++mi) {
      int row = wr * 64 + mi * 16 + (lane & 15);
      int sl = (((lane >> 4) ^ (row & 3)) << 3);
      afh[mi] = *(const bfrag8*)(AsH + row * 32 + sl);
      if (SPLIT) afl[mi] = *(const bfrag8*)(AsL + row * 32 + sl);
    }
#pragma unroll
    for (int ni = 0; ni < 4; ++ni) {
      int row = wc * 64 + ni * 16 + (lane & 15);
      int sl = (((lane >> 4) ^ (row & 3)) << 3);
      bfh[ni] = *(const bfrag8*)(BsH + row * 32 + sl);
      if (SPLIT) bfl[ni] = *(const bfrag8*)(BsL + row * 32 + sl);
    }
#pragma unroll
    for (int mi = 0; mi < 4; ++mi)
#pragma unroll
      for (int ni = 0; ni < 4; ++ni) {
        acc[mi][ni] = __builtin_amdgcn_mfma_f32_16x16x32_bf16(
            afh[mi], bfh[ni], acc[mi][ni], 0, 0, 0);
        if (SPLIT) {
          acc[mi][ni] = __builtin_amdgcn_mfma_f32_16x16x32_bf16(
              afh[mi], bfl[ni], acc[mi][ni], 0, 0, 0);
          acc[mi][ni] = __builtin_amdgcn_mfma_f32_16x16x32_bf16(
              afl[mi], bfh[ni], acc[mi][ni], 0, 0, 0);
        }
      }
    __syncthreads();
  }
  Cf += (long)bz * NN * F;
#pragma unroll
  for (int mi = 0; mi < 4; ++mi) {
    int rowb = m0 + wr * 64 + mi * 16 + ((lane >> 4) << 2);
#pragma unroll
    for (int ni = 0; ni < 4; ++ni) {
      int col = n0 + wc * 64 + ni * 16 + (lane & 15);
      float bcol = bias[col];
#pragma unroll
      for (int q = 0; q < 4; ++q) {
        float dm = dvv[(bz << 10) + rowb + q];
        float xwv = XW[((long)(bz << 10) + rowb + q) * F + col];
        float v = dm * (acc[mi][ni][q] + dm * xwv) + bcol;
        if (RELU) v = fmaxf(v, 0.f);
        Cf[(long)(rowb + q) * F + col] = v;
      }
    }
  }
}

// ---- split-bf16 3-product NT MFMA Gram + fused C^T write -------------------
__global__ __launch_bounds__(256) void k_mfma_gram(
    const unsigned short* __restrict__ Ah, const unsigned short* __restrict__ Al,
    const unsigned short* __restrict__ Bh, const unsigned short* __restrict__ Bl,
    const float* __restrict__ xx, const float* __restrict__ yy,
    float* __restrict__ Cf, float* __restrict__ Ct) {
  __shared__ unsigned short AsH[128 * 32], AsL[128 * 32];
  __shared__ unsigned short BsH[128 * 32], BsL[128 * 32];
  int bz = blockIdx.z;
  long boff = (long)bz * NN * FIN;
  Ah += boff; Al += boff; Bh += boff; Bl += boff;
  const float* xxb = xx + (bz << 10);
  const float* yyb = yy + (bz << 10);
  int m0 = blockIdx.y * 128, n0 = blockIdx.x * 128;
  int tid = threadIdx.x, lane = tid & 63, w = tid >> 6;
  int wr = w >> 1, wc = w & 1;
  facc4 acc[4][4];
#pragma unroll
  for (int i = 0; i < 4; ++i)
#pragma unroll
    for (int j = 0; j < 4; ++j)
#pragma unroll
      for (int q = 0; q < 4; ++q) acc[i][j][q] = 0.f;

  int rA0 = w * 16 + (lane >> 2);
  int kslot = lane & 3;

  for (int k0 = 0; k0 < FIN; k0 += 32) {
#pragma unroll
    for (int i = 0; i < 2; ++i) {
      int row = i * 64 + rA0;
      int ks = (kslot ^ (row & 3)) << 3;
      long ga = (long)(m0 + row) * FIN + k0 + ks;
      long gb = (long)(n0 + row) * FIN + k0 + ks;
      int ld = (i * 64 + w * 16) * 32;
      GLOAD16(Ah + ga, AsH + ld);
      GLOAD16(Al + ga, AsL + ld);
      GLOAD16(Bh + gb, BsH + ld);
      GLOAD16(Bl + gb, BsL + ld);
    }
    __syncthreads();
    bfrag8 afh[4], afl[4], bfh[4], bfl[4];
#pragma unroll
    for (int mi = 0; mi < 4; ++mi) {
      int row = wr * 64 + mi * 16 + (lane & 15);
      int sl = (((lane >> 4) ^ (row & 3)) << 3);
      afh[mi] = *(const bfrag8*)(AsH + row * 32 + sl);
      afl[mi] = *(const bfrag8*)(AsL + row * 32 + sl);
    }
#pragma unroll
    for (int ni = 0; ni < 4; ++ni) {
      int row = wc * 64 + ni * 16 + (lane & 15);
      int sl = (((lane >> 4) ^ (row & 3)) << 3);
      bfh[ni] = *(const bfrag8*)(BsH + row * 32 + sl);
      bfl[ni] = *(const bfrag8*)(BsL + row * 32 + sl);
    }
#pragma unroll
    for (int mi = 0; mi < 4; ++mi)
#pragma unroll
      for (int ni = 0; ni < 4; ++ni) {
        acc[mi][ni] = __builtin_amdgcn_mfma_f32_16x16x32_bf16(
            afh[mi], bfh[ni], acc[mi][ni], 0, 0, 0);
        acc[mi][ni] = __builtin_amdgcn_mfma_f32_16x16x32_bf16(
            afh[mi], bfl[ni], acc[mi][ni], 0, 0, 0);
        acc[mi][ni] = __builtin_amdgcn_mfma_f32_16x16x32_bf16(
            afl[mi], bfh[ni], acc[mi][ni], 0, 0, 0);
      }
    __syncthreads();
  }
  Cf += (long)bz * NN * NN;
  Ct += (long)bz * NN * NN;
#pragma unroll
  for (int mi = 0; mi < 4; ++mi) {
    int rowb = m0 + wr * 64 + mi * 16 + ((lane >> 4) << 2);
#pragma unroll
    for (int ni = 0; ni < 4; ++ni) {
      int col = n0 + wc * 64 + ni * 16 + (lane & 15);
      float yv = yyb[col];
      float4 tv;
#pragma unroll
      for (int q = 0; q < 4; ++q) {
        float v = xxb[rowb + q] + yv - 2.f * acc[mi][ni][q];
        Cf[(long)(rowb + q) * NN + col] = v;
        ((float*)&tv)[q] = v;
      }
      *(float4*)(Ct + (long)col * NN + rowb) = tv;   // transposed write
    }
  }
}

// ---------------- s0 = cx @ Watt  (per-row dot, HID=128) --------------------
__global__ __launch_bounds__(256) void k_rowdot(const float* __restrict__ X,
                                                const float* __restrict__ w,
                                                float* __restrict__ out) {
  int t = threadIdx.x; int lane = t & 63; int wv = t >> 6;
  int row = blockIdx.x * 4 + wv;
  const float* xr = X + (long)row * HIDN;
  float s = xr[lane] * w[lane] + xr[lane + 64] * w[lane + 64];
  s = wred_sum(s);
  if (lane == 0) out[row] = s;
}

// ---- alpha (4 rows/block) = sigmoid((gcn_norm(adj) @ s0 + batt)^2) ---------
__global__ __launch_bounds__(256) void k_alpha4(const float* __restrict__ adj,
                                                const float* __restrict__ dv,
                                                const float* __restrict__ s0,
                                                const float* __restrict__ batt,
                                                float* __restrict__ alpha) {
  int r0 = blockIdx.x << 2; int b = r0 >> 10; int i0 = r0 & (NN - 1);
  int t = threadIdx.x, lane = t & 63, wv = t >> 6;
  float4 d4 = ((const float4*)(dv + (b << 10)))[t];
  float4 s4 = ((const float4*)(s0 + (b << 10)))[t];
  float w4[4];
  w4[0] = d4.x * s4.x; w4[1] = d4.y * s4.y; w4[2] = d4.z * s4.z; w4[3] = d4.w * s4.w;
  __shared__ float sm[4][4];
#pragma unroll
  for (int r = 0; r < 4; ++r) {
    float4 a4 = ((const float4*)(adj + (long)(r0 + r) * NN))[t];
    float dot = a4.x * w4[0] + a4.y * w4[1] + a4.z * w4[2] + a4.w * w4[3];
    int i = i0 + r;
    if ((i >> 2) == t) dot += w4[i & 3];   // +I diagonal
    dot = wred_sum(dot);
    if (lane == 0) sm[wv][r] = dot;
  }
  __syncthreads();
  if (t < 4) {
    float dot = sm[0][t] + sm[1][t] + sm[2][t] + sm[3][t];
    float tt = dv[r0 + t] * dot + batt[0];
    alpha[r0 + t] = 1.f / (1.f + __expf(-tt * tt));
  }
}

// ---------------- per-batch k-th largest via bitonic sort -------------------
__global__ __launch_bounds__(512) void k_topk(const float* __restrict__ alpha,
                                              float* __restrict__ cut) {
  __shared__ float smv[NN];
  int b = blockIdx.x; int t = threadIdx.x;
  smv[t] = alpha[(b << 10) + t];
  smv[t + 512] = alpha[(b << 10) + t + 512];
  __syncthreads();
  for (int k2 = 2; k2 <= NN; k2 <<= 1) {
    for (int j2 = k2 >> 1; j2 > 0; j2 >>= 1) {
      int i = ((t / j2) * (j2 << 1)) + (t % j2);
      int ixj = i + j2;
      bool up = ((i & k2) == 0);
      float a = smv[i], c = smv[ixj];
      if ((a > c) == up) { smv[i] = c; smv[ixj] = a; }
      __syncthreads();
    }
  }
  if (t == 0) cut[b] = smv[NN - KTOP];
}

// ---- S build (4 rows/block): rmask_i d_i d_j (adj+I) gate_j, row-L1 norm ---
__global__ __launch_bounds__(256) void k_sbuild4(const float* __restrict__ adj,
                                                 const float* __restrict__ dv,
                                                 const float* __restrict__ rm,
                                                 const float* __restrict__ alpha,
                                                 const float* __restrict__ cut,
                                                 float* __restrict__ S) {
  int r0 = blockIdx.x << 2; int b = r0 >> 10; int i0 = r0 & (NN - 1);
  int t = threadIdx.x, lane = t & 63, wv = t >> 6;
  float cb = cut[b];
  float4 d4 = ((const float4*)(dv + (b << 10)))[t];
  float4 al4 = ((const float4*)(alpha + (b << 10)))[t];
  float4 dg;
  dg.x = d4.x * fmaxf(al4.x + 1e-7f - cb, 0.f);
  dg.y = d4.y * fmaxf(al4.y + 1e-7f - cb, 0.f);
  dg.z = d4.z * fmaxf(al4.z + 1e-7f - cb, 0.f);
  dg.w = d4.w * fmaxf(al4.w + 1e-7f - cb, 0.f);
  __shared__ float sm[4][4];
  __shared__ float sinv[4];
  float4 vals[4];
#pragma unroll
  for (int r = 0; r < 4; ++r) {
    float di = dv[r0 + r] * rm[r0 + r];
    float4 a4 = ((const float4*)(adj + (long)(r0 + r) * NN))[t];
    int i = i0 + r;
    if ((i >> 2) == t) ((float*)&a4)[i & 3] += 1.f;
    vals[r].x = di * dg.x * a4.x; vals[r].y = di * dg.y * a4.y;
    vals[r].z = di * dg.z * a4.z; vals[r].w = di * dg.w * a4.w;
    float s = (fabsf(vals[r].x) + fabsf(vals[r].y)) +
              (fabsf(vals[r].z) + fabsf(vals[r].w));
    s = wred_sum(s);
    if (lane == 0) sm[wv][r] = s;
  }
  __syncthreads();
  if (t < 4) sinv[t] = 1.f / fmaxf(sm[0][t] + sm[1][t] + sm[2][t] + sm[3][t], 1e-12f);
  __syncthreads();
#pragma unroll
  for (int r = 0; r < 4; ++r) {
    float inv = sinv[r];
    float4 o; o.x = vals[r].x * inv; o.y = vals[r].y * inv;
    o.z = vals[r].z * inv; o.w = vals[r].w * inv;
    ((float4*)(S + (long)(r0 + r) * NN))[t] = o;
  }
}

// ---------------- K-split fp32 GEMM (TA=0,TB=0), partials out ---------------
template<int GCN>
__global__ __launch_bounds__(256) void k_gemm_ks(
    const float* __restrict__ A, const float* __restrict__ Bm, float* __restrict__ P,
    int M, int Nn, int K, int KS, long sA, long sB,
    const float* __restrict__ dv) {
  __shared__ float As[8][132];
  __shared__ float Bs[8][132];
  int z = blockIdx.z;
  int b = z / KS, ks = z % KS;
  int KC = K / KS;
  A += (long)b * sA; Bm += (long)b * sB;
  const float* dvb = GCN ? (dv + (long)b * NN) : nullptr;
  int m0 = blockIdx.y * 128, n0 = blockIdx.x * 128;
  int tid = threadIdx.x;
  int tx = tid & 15, ty = tid >> 4;
  float acc[8][8];
#pragma unroll
  for (int i = 0; i < 8; i++)
#pragma unroll
    for (int j = 0; j < 8; j++) acc[i][j] = 0.f;

  float drow = 0.f;
  if (GCN) drow = dvb[m0 + (tid >> 1)];

  for (int k0 = ks * KC; k0 < ks * KC + KC; k0 += 8) {
    {
      int r = tid >> 1, c4 = (tid & 1) * 4;
      float4 av = *(const float4*)(A + (long)(m0 + r) * K + k0 + c4);
      float a4[4] = {av.x, av.y, av.z, av.w};
      if (GCN) {
#pragma unroll
        for (int q = 0; q < 4; ++q) {
          int gj = k0 + c4 + q;
          float val = a4[q] + ((m0 + r) == gj ? 1.f : 0.f);
          a4[q] = drow * dvb[gj] * val;
        }
      }
      As[c4 + 0][r] = a4[0]; As[c4 + 1][r] = a4[1];
      As[c4 + 2][r] = a4[2]; As[c4 + 3][r] = a4[3];
    }
    {
      int kr = tid >> 5, c4 = (tid & 31) * 4;
      float4 bv = *(const float4*)(Bm + (long)(k0 + kr) * Nn + n0 + c4);
      *(float4*)&Bs[kr][c4] = bv;
    }
    __syncthreads();
#pragma unroll
    for (int k = 0; k < 8; ++k) {
      float av[8], bv[8];
      *(float4*)&av[0] = *(const float4*)&As[k][ty * 8];
      *(float4*)&av[4] = *(const float4*)&As[k][ty * 8 + 4];
      *(float4*)&bv[0] = *(const float4*)&Bs[k][tx * 8];
      *(float4*)&bv[4] = *(const float4*)&Bs[k][tx * 8 + 4];
#pragma unroll
      for (int i = 0; i < 8; i++)
#pragma unroll
        for (int j = 0; j < 8; j++)
          acc[i][j] = fmaf(av[i], bv[j], acc[i][j]);
    }
    __syncthreads();
  }
  float* Pz = P + (long)z * M * Nn;
#pragma unroll
  for (int i = 0; i < 8; ++i) {
    int m = m0 + ty * 8 + i;
    float* prow = Pz + (long)m * Nn + n0 + tx * 8;
    *(float4*)&prow[0] = *(float4*)&acc[i][0];
    *(float4*)&prow[4] = *(float4*)&acc[i][4];
  }
}

// ---------------- reduce K-split partials (+bias, +relu) --------------------
template<int RELU, int BIAS>
__global__ __launch_bounds__(256) void k_red_bias(
    const float* __restrict__ P, const float* __restrict__ bias,
    float* __restrict__ out, int Nn, int KS, long chunk) {
  long u = ((long)blockIdx.x * 256 + threadIdx.x) * 4;
  long b = u / chunk; long rem = u % chunk;
  const float* p = P + b * KS * chunk + rem;
  float4 s = *(const float4*)p;
  for (int k = 1; k < KS; ++k) {
    float4 q = *(const float4*)(p + (long)k * chunk);
    s.x += q.x; s.y += q.y; s.z += q.z; s.w += q.w;
  }
  if (BIAS) {
    int n = (int)(rem % Nn);
    s.x += bias[n]; s.y += bias[n + 1]; s.z += bias[n + 2]; s.w += bias[n + 3];
  }
  if (RELU) {
    s.x = fmaxf(s.x, 0.f); s.y = fmaxf(s.y, 0.f);
    s.z = fmaxf(s.z, 0.f); s.w = fmaxf(s.w, 0.f);
  }
  *(float4*)(out + u) = s;
}

// ---------------- column mean over nodes ------------------------------------
__global__ __launch_bounds__(256) void k_colmean(const float* __restrict__ X, int Fd,
                                                 float* __restrict__ out) {
  int nb = Fd >> 6;
  int b = blockIdx.x / nb; int f0 = (blockIdx.x % nb) << 6;
  int t = threadIdx.x;
  int f = f0 + (t & 63); int rc = t >> 6;
  const float* xb = X + (long)b * NN * Fd;
  float s = 0.f;
  for (int i = rc * 256; i < rc * 256 + 256; ++i) s += xb[(long)i * Fd + f];
  __shared__ float sm[256];
  sm[t] = s; __syncthreads();
  if (t < 64) out[b * Fd + f] = (sm[t] + sm[t + 64] + sm[t + 128] + sm[t + 192]) * (1.f / NN);
}

// ---------------- squared row norms -----------------------------------------
__global__ __launch_bounds__(256) void k_sqnorm(const float* __restrict__ X, int Fd,
                                                float* __restrict__ out) {
  int t = threadIdx.x; int lane = t & 63; int wv = t >> 6;
  int row = blockIdx.x * 4 + wv;
  const float* xr = X + (long)row * Fd;
  float s = 0.f;
  for (int f = lane; f < Fd; f += 64) { float v = xr[f]; s = fmaf(v, v, s); }
  s = wred_sum(s);
  if (lane == 0) out[row] = s;
}

// ======================= persistent register-resident Sinkhorn ==============
// 256 blocks x 512 thr. Lane owns 64 cols of one row of C AND of C^T in VGPRs
// (pre-scaled by 1/eps). Per pass: read 4KB dual vector (L1), 16-lane LSE.
// Group barriers (32 blocks = 1 batch): slot-per-block, no atomic contention.

static __device__ __forceinline__ void group_bar(int* __restrict__ slots,
                                                 int* __restrict__ gens,
                                                 int bid, int grp, int t, int g1) {
  __syncthreads();
  if (t == 0) {
    __threadfence();
    __hip_atomic_store(&slots[bid * 16], g1, __ATOMIC_RELEASE,
                       __HIP_MEMORY_SCOPE_AGENT);
  }
  int mbid = grp << 5;
  if (bid == mbid) {
    if (t < 64) {
      int idx = (mbid + (t & 31)) * 16;
      int iter = 0;
      while (true) {
        int m = __hip_atomic_load(&slots[idx], __ATOMIC_ACQUIRE,
                                  __HIP_MEMORY_SCOPE_AGENT);
#pragma unroll
        for (int msk = 1; msk <= 16; msk <<= 1) {
          int o = __shfl_xor(m, msk);
          m = m < o ? m : o;
        }
        if (m >= g1 || ++iter > (1 << 22)) break;
        __builtin_amdgcn_s_sleep(2);
      }
      if (t == 0)
        __hip_atomic_store(&gens[grp * 16], g1, __ATOMIC_RELEASE,
                           __HIP_MEMORY_SCOPE_AGENT);
    }
    __syncthreads();
  } else {
    if (t == 0) {
      int iter = 0;
      while (__hip_atomic_load(&gens[grp * 16], __ATOMIC_ACQUIRE,
                               __HIP_MEMORY_SCOPE_AGENT) < g1) {
        if (++iter > (1 << 22)) break;
        __builtin_amdgcn_s_sleep(4);
      }
    }
    __syncthreads();
  }
}

// One LSE half-pass for this lane's row slice (values pre-scaled by 1/eps).
template<int LOSS>
static __device__ __forceinline__ void pass_reg(const float4 (&Cr)[16],
    const float* __restrict__ vinb, float* __restrict__ uout,
    int jc, int row, float* __restrict__ lossacc) {
  const float4* vp = (const float4*)vinb + jc * 16;
  float mx = -3.0e38f;
#pragma unroll
  for (int k = 0; k < 16; ++k) {
    float4 v4 = vp[k];
    float ax = v4.x - Cr[k].x, ay = v4.y - Cr[k].y;
    float az = v4.z - Cr[k].z, aw = v4.w - Cr[k].w;
    mx = fmaxf(mx, fmaxf(fmaxf(ax, ay), fmaxf(az, aw)));
  }
#pragma unroll
  for (int m = 1; m <= 8; m <<= 1) mx = fmaxf(mx, __shfl_xor(mx, m));
  float ls = 0.f, ld = 0.f;
#pragma unroll
  for (int k = 0; k < 16; ++k) {
    float4 v4 = vp[k];
    float e;
    e = __expf(v4.x - Cr[k].x - mx); ls += e; if (LOSS) ld = fmaf(e, Cr[k].x, ld);
    e = __expf(v4.y - Cr[k].y - mx); ls += e; if (LOSS) ld = fmaf(e, Cr[k].y, ld);
    e = __expf(v4.z - Cr[k].z - mx); ls += e; if (LOSS) ld = fmaf(e, Cr[k].z, ld);
    e = __expf(v4.w - Cr[k].w - mx); ls += e; if (LOSS) ld = fmaf(e, Cr[k].w, ld);
  }
#pragma unroll
  for (int m = 1; m <= 8; m <<= 1) {
    ls += __shfl_xor(ls, m);
    if (LOSS) ld += __shfl_xor(ld, m);
  }
  if (jc == 0) {
    uout[row] = LOG_MU - (mx + __logf(ls));   // scaled dual u/eps
    if (LOSS) *lossacc += (ld / ls) * (1.0f / 1024.0f);
  }
}

__global__ __launch_bounds__(512, 2) void k_sink_reg(
    const float* __restrict__ Cm, const float* __restrict__ Ct,
    float* __restrict__ uvv, float* __restrict__ vvv,
    float* __restrict__ part, float* __restrict__ oloss,
    int* __restrict__ slots1, int* __restrict__ gens, int* __restrict__ slots2) {
  int bid = blockIdx.x, t = threadIdx.x, lane = t & 63, wvi = t >> 6;
  int jc = lane & 15;
  int row = bid * 32 + wvi * 4 + (lane >> 4);
  int b = bid >> 5;
  float4 Creg[16], Ctreg[16];
  {
    const float4* cp = (const float4*)(Cm + (long)row * NN) + jc * 16;
    const float4* tp = (const float4*)(Ct + (long)row * NN) + jc * 16;
#pragma unroll
    for (int k = 0; k < 16; ++k) {
      float4 c = cp[k], ct = tp[k];
      Creg[k].x = c.x * INV_EPS;  Creg[k].y = c.y * INV_EPS;
      Creg[k].z = c.z * INV_EPS;  Creg[k].w = c.w * INV_EPS;
      Ctreg[k].x = ct.x * INV_EPS; Ctreg[k].y = ct.y * INV_EPS;
      Ctreg[k].z = ct.z * INV_EPS; Ctreg[k].w = ct.w * INV_EPS;
    }
  }
  const float* ub = uvv + (b << 10);
  const float* vb = vvv + (b << 10);
  float lossacc = 0.f;
  int g1 = 1;
  for (int it = 0; it < NITER; ++it) {
    pass_reg<0>(Creg, vb, uvv, jc, row, nullptr);          // u update
    group_bar(slots1, gens, bid, b, t, g1); ++g1;
    if (it < NITER - 1) {
      pass_reg<0>(Ctreg, ub, vvv, jc, row, nullptr);       // v update
      group_bar(slots1, gens, bid, b, t, g1); ++g1;
    } else {
      pass_reg<1>(Ctreg, ub, vvv, jc, row, &lossacc);      // v + fused loss
    }
  }
  // per-block loss partial
  float s = lossacc;
  s = wred_sum(s);
  __shared__ float lsm[8];
  if (lane == 0) lsm[wvi] = s;
  __syncthreads();
  if (t == 0) {
    float ps = 0.f;
#pragma unroll
    for (int i = 0; i < 8; ++i) ps += lsm[i];
    part[bid] = ps;
    __threadfence();
    __hip_atomic_store(&slots2[bid * 16], 1, __ATOMIC_RELEASE,
                       __HIP_MEMORY_SCOPE_AGENT);
  }
  if (bid == 0) {
    if (t < 64) {
      int iter = 0;
      while (true) {
        int m = 1 << 30;
#pragma unroll
        for (int q = 0; q < 4; ++q) {
          int v = __hip_atomic_load(&slots2[(t * 4 + q) * 16], __ATOMIC_ACQUIRE,
                                    __HIP_MEMORY_SCOPE_AGENT);
          m = v < m ? v : m;
        }
#pragma unroll
        for (int msk = 1; msk <= 32; msk <<= 1) {
          int o = __shfl_xor(m, msk);
          m = m < o ? m : o;
        }
        if (m >= 1 || ++iter > (1 << 22)) break;
        __builtin_amdgcn_s_sleep(2);
      }
    }
    __syncthreads();
    float s2 = (t < SNB) ? part[t] : 0.f;
    s2 = wred_sum(s2);
    __shared__ float sm2[8];
    if (lane == 0) sm2[wvi] = s2;
    __syncthreads();
    if (t == 0) {
      float tot = 0.f;
#pragma unroll
      for (int i = 0; i < 8; ++i) tot += sm2[i];
      oloss[0] = tot * EPS_S;   // undo the 1/eps scaling of C' in ld
    }
  }
}

extern "C" void kernel_launch(void* const* d_in, const int* in_sizes, int n_in,
                              void* d_out, int out_size, void* d_ws, size_t ws_size,
                              hipStream_t stream) {
  const float* x    = (const float*)d_in[0];
  const float* adj  = (const float*)d_in[1];
  const float* W1   = (const float*)d_in[3];
  const float* b1   = (const float*)d_in[4];
  const float* Watt = (const float*)d_in[5];
  const float* batt = (const float*)d_in[6];
  const float* W2   = (const float*)d_in[7];
  const float* b2   = (const float*)d_in[8];

  float* out = (float*)d_out;
  float* xs0   = out;                    // [8,128]
  float* xs1   = out + 1024;             // [8,256]
  float* oadj0 = out + 3072;             // [8,1024,1024]
  float* oadj1 = oadj0 + 8388608;
  float* oadj2 = oadj1 + 8388608;        // adj_bf scratch until adj2 written
  float* oS0   = oadj2 + 8388608;
  float* oS1   = oS0 + 8388608;
  float* oloss = oS1 + 8388608;          // [1]

  float* ws   = (float*)d_ws;
  float* wXW  = ws;                       // 2,097,152 (XW1 then XW2)
  float* wCXA = wXW + 2097152;            // 1,048,576 (x1, later emb2)
  float* wCXB = wCXA + 1048576;           // 1,048,576 (emb1)
  float* wR   = wCXB + 1048576;           // 8,388,608 (tmp_bf | P | Cmat)
  float* wX2  = wR + 8388608;             // 2,097,152 (x2)
  float* wStf = wX2 + 2097152;            // 4,194,304 (x_bf/St/Bg2/x-splits)
  float* wCxtf= wStf + 4194304;           // 524,288   (Bg1 / cxt)
  float* wCt  = wCxtf + 524288;           // 8,388,608 (a2h+a2l, then C^T)
  float* smb  = wCt + 8388608;

  unsigned short* tmp_bf = (unsigned short*)wR;                 // 16.7MB half
  unsigned short* a2h    = (unsigned short*)wCt;                // 8,388,608 sh
  unsigned short* a2l    = a2h + 8388608;                       // 8,388,608 sh
  unsigned short* adj_bf = (unsigned short*)oadj2;
  unsigned short* St     = (unsigned short*)wStf;
  unsigned short* cxt    = (unsigned short*)wCxtf;
  unsigned short* x_bf   = (unsigned short*)wStf;               // pre-coarsen
  unsigned short* Bg1    = (unsigned short*)wCxtf;
  unsigned short* Bg2h   = (unsigned short*)wStf;               // post-adj2
  unsigned short* Bg2l   = (unsigned short*)(wStf + 2097152);
  unsigned short* xh  = (unsigned short*)wStf;                  // sinkhorn phase
  unsigned short* xl  = xh + 2097152;
  unsigned short* x2h = xh + 4194304;
  unsigned short* x2l = xh + 6291456;
  float* Cmat = wR;
  float* d0 = smb;            float* rm0 = smb + 8192;
  float* d1 = smb + 16384;    float* rm1 = smb + 24576;
  float* d2 = smb + 32768;    float* rm2 = smb + 40960;
  float* s0v = smb + 49152;   float* alp = smb + 57344;
  float* xxv = smb + 65536;   float* yyv = smb + 73728;
  float* uv  = smb + 81920;   float* vv  = smb + 90112;   // contiguous
  float* cutv = smb + 98304;  float* part = smb + 98368;  // 256
  unsigned short* W1t = (unsigned short*)(smb + 98624);    // 32768 shorts
  int* ibar = (int*)(smb + 115008);
  int* slots1 = ibar;                 // 256*16 ints
  int* gens   = ibar + 4096;          // 8*16 ints
  int* slots2 = ibar + 4224;          // 256*16 ints

  // rowstats on adj + fused bf16 copy (into oadj2 region) + fp32 copy (oadj0)
  k_rowstats4<1, 1><<<2048, 256, 0, stream>>>(adj, d0, rm0, adj_bf, oadj0);

  // ---- GCN1 (MFMA): x1 = relu(d*(adj_bf @ (d.*XW1) + d*XW1_diag) + b1) ----
  k_f2b<<<2048, 256, 0, stream>>>(x, x_bf);
  k_w1t<<<128, 256, 0, stream>>>(W1, W1t);
  k_mfma_nt<1, 0><<<dim3(1, 64, 1), 256, 0, stream>>>(x_bf, W1t, wXW, nullptr,
      nullptr, 256, 256, 256, 128, 0L, 0L, 0L);
  k_stc<0><<<dim3(16, 2, 8), 256, 0, stream>>>(wXW, d0, Bg1, nullptr, HIDN);
  k_mfma_gcn<0, 1><<<dim3(1, 8, 8), 256, 0, stream>>>(adj_bf, nullptr, Bg1,
      nullptr, d0, wXW, b1, wCXA, HIDN);
  k_colmean<<<16, 256, 0, stream>>>(wCXA, HIDN, xs0);

  // ---- coarsen layer 1 ----
  k_rowdot<<<2048, 256, 0, stream>>>(wCXA, Watt, s0v);
  k_alpha4<<<2048, 256, 0, stream>>>(adj, d0, s0v, batt, alp);
  k_topk<<<8, 512, 0, stream>>>(alp, cutv);
  k_sbuild4<<<2048, 256, 0, stream>>>(adj, d0, rm0, alp, cutv, oS0);
  k_transp<<<dim3(16, 16, 8), 256, 0, stream>>>(oS0, St, 1024, 1024);
  k_transp<<<dim3(2, 16, 8), 256, 0, stream>>>(wCXA, cxt, 1024, 128);
  k_mfma_nt<1, 0><<<dim3(1, 8, 8), 256, 0, stream>>>(St, cxt, wCXB, nullptr,
      nullptr, 1024, 1024, 1024, 128, 1048576L, 131072L, 131072L);
  k_mfma_nt<0, 1><<<dim3(8, 8, 8), 256, 0, stream>>>(St, adj_bf, nullptr, tmp_bf,
      nullptr, 1024, 1024, 1024, 1024, 1048576L, 1048576L, 1048576L);
  k_mfma_nt<1, 1><<<dim3(8, 8, 8), 256, 0, stream>>>(tmp_bf, St, oadj1, adj_bf,
      nullptr, 1024, 1024, 1024, 1024, 1048576L, 1048576L, 1048576L);
  k_rowstats4<0, 0><<<2048, 256, 0, stream>>>(oadj1, d1, rm1, nullptr, nullptr);

  // ---- coarsen layer 2 ----
  k_rowdot<<<2048, 256, 0, stream>>>(wCXB, Watt, s0v);
  k_alpha4<<<2048, 256, 0, stream>>>(oadj1, d1, s0v, batt, alp);
  k_topk<<<8, 512, 0, stream>>>(alp, cutv);
  k_sbuild4<<<2048, 256, 0, stream>>>(oadj1, d1, rm1, alp, cutv, oS1);
  k_transp<<<dim3(16, 16, 8), 256, 0, stream>>>(oS1, St, 1024, 1024);
  k_transp<<<dim3(2, 16, 8), 256, 0, stream>>>(wCXB, cxt, 1024, 128);
  k_mfma_nt<1, 0><<<dim3(1, 8, 8), 256, 0, stream>>>(St, cxt, wCXA, nullptr,
      nullptr, 1024, 1024, 1024, 128, 1048576L, 131072L, 131072L);
  k_mfma_nt<0, 1><<<dim3(8, 8, 8), 256, 0, stream>>>(St, adj_bf, nullptr, tmp_bf,
      nullptr, 1024, 1024, 1024, 1024, 1048576L, 1048576L, 1048576L);
  // adj2 -> fp32 output + hi/lo bf16 pair (in wCt region) for split final GCN
  k_mfma_nt<1, 2><<<dim3(8, 8, 8), 256, 0, stream>>>(tmp_bf, St, oadj2, a2h,
      a2l, 1024, 1024, 1024, 1024, 1048576L, 1048576L, 1048576L);
  k_rowstats4<0, 0><<<2048, 256, 0, stream>>>(oadj2, d2, rm2, nullptr, nullptr);

  // ---- final GCN (split-bf16 MFMA): x2 = d*(A2@(d.*XW2) + d*XW2_diag) + b2 --
  k_gemm_ks<0><<<dim3(2, 64, 2), 256, 0, stream>>>(wCXA, W2, wR, 8192, FIN, HIDN,
      2, 0L, 0L, nullptr);   // P partials in wR first half (tmp_bf dead)
  k_red_bias<0, 0><<<2048, 256, 0, stream>>>(wR, nullptr, wXW, FIN, 2, 2097152L);
  k_stc<1><<<dim3(16, 4, 8), 256, 0, stream>>>(wXW, d2, Bg2h, Bg2l, FIN);
  k_mfma_gcn<1, 0><<<dim3(2, 8, 8), 256, 0, stream>>>(a2h, a2l, Bg2h, Bg2l,
      d2, wXW, b2, wX2, FIN);
  k_colmean<<<32, 256, 0, stream>>>(wX2, FIN, xs1);

  // ---- Sinkhorn: C via split-bf16 MFMA Gram (+fused C^T), reg-resident solve
  k_sqnorm<<<2048, 256, 0, stream>>>(x, FIN, xxv);
  k_sqnorm<<<2048, 256, 0, stream>>>(wX2, FIN, yyv);
  k_split2<<<2048, 256, 0, stream>>>(x, xh, xl);
  k_split2<<<2048, 256, 0, stream>>>(wX2, x2h, x2l);
  k_mfma_gram<<<dim3(8, 8, 8), 256, 0, stream>>>(xh, xl, x2h, x2l, xxv, yyv,
      Cmat, wCt);
  hipMemsetAsync(uv, 0, (size_t)2 * 8192 * 4, stream);
  hipMemsetAsync(ibar, 0, (size_t)(4096 + 128 + 4096) * 4, stream);
  k_sink_reg<<<SNB, 512, 0, stream>>>(Cmat, wCt, uv, vv, part, oloss,
                                      slots1, gens, slots2);
}

// Round 8
// 749.262 us; speedup vs baseline: 2.2472x; 1.7881x over previous
//
#include <hip/hip_runtime.h>
#include <math.h>

// Problem constants (fixed by the reference)
#define BN   8
#define NN   1024
#define FIN  256
#define HIDN 128
#define KTOP 513          // int(1024*0.5)+1
#define NITER 20          // opt_epochs in setup_inputs
#define EPS_S 0.01f
#define INV_EPS 100.0f
#define LOG_MU (-6.9314718055994531f)   // -log(1024)
#define SNB 256           // blocks in persistent sinkhorn kernel

typedef __attribute__((ext_vector_type(8))) short bfrag8;   // 8 bf16 (4 VGPR)
typedef __attribute__((ext_vector_type(4))) float facc4;    // MFMA accumulator

#define GLOAD16(g, l) __builtin_amdgcn_global_load_lds( \
    (const __attribute__((address_space(1))) unsigned int*)(g), \
    (__attribute__((address_space(3))) unsigned int*)(l), 16, 0, 0)

static __device__ __forceinline__ float wred_sum(float s) {
#pragma unroll
  for (int o = 32; o > 0; o >>= 1) s += __shfl_xor(s, o);
  return s;
}
static __device__ __forceinline__ unsigned short f2b(float f) {
  unsigned int u = __float_as_uint(f);
  u += 0x7fff + ((u >> 16) & 1);      // RNE
  return (unsigned short)(u >> 16);
}
static __device__ __forceinline__ float b2f(unsigned short h) {
  return __uint_as_float((unsigned int)h << 16);
}

// ---- rowstats (4 rows/block): d = rsqrt(max(rowsum+1,1)), rmask ------------
template<int WRBF, int WCOPY>
__global__ __launch_bounds__(256) void k_rowstats4(const float* __restrict__ adj,
                                                   float* __restrict__ dv,
                                                   float* __restrict__ rm,
                                                   unsigned short* __restrict__ abf,
                                                   float* __restrict__ ocopy) {
  int r0 = blockIdx.x << 2;
  int t = threadIdx.x, lane = t & 63, wv = t >> 6;
  __shared__ float sm[4][4];
#pragma unroll
  for (int r = 0; r < 4; ++r) {
    float4 v = ((const float4*)(adj + (long)(r0 + r) * NN))[t];
    if (WRBF) {
      ushort4 h; h.x = f2b(v.x); h.y = f2b(v.y); h.z = f2b(v.z); h.w = f2b(v.w);
      *(ushort4*)(abf + (long)(r0 + r) * NN + t * 4) = h;
    }
    if (WCOPY) ((float4*)(ocopy + (long)(r0 + r) * NN))[t] = v;
    float s = (v.x + v.y) + (v.z + v.w);
    s = wred_sum(s);
    if (lane == 0) sm[wv][r] = s;
  }
  __syncthreads();
  if (t < 4) {
    float tot = sm[0][t] + sm[1][t] + sm[2][t] + sm[3][t];
    dv[r0 + t] = rsqrtf(fmaxf(tot + 1.0f, 1.0f));
    rm[r0 + t] = tot > 0.0f ? 1.0f : 0.0f;
  }
}

// ---------------- fp32 -> bf16 elementwise ----------------------------------
__global__ __launch_bounds__(256) void k_f2b(const float* __restrict__ X,
                                             unsigned short* __restrict__ Y) {
  long i = ((long)blockIdx.x * 256 + threadIdx.x) * 4;
  float4 v = *(const float4*)(X + i);
  Y[i] = f2b(v.x); Y[i + 1] = f2b(v.y); Y[i + 2] = f2b(v.z); Y[i + 3] = f2b(v.w);
}

// ---- W1 [256][128] fp32 -> W1t [128][256] bf16 -----------------------------
__global__ __launch_bounds__(256) void k_w1t(const float* __restrict__ W,
                                             unsigned short* __restrict__ Wt) {
  int idx = blockIdx.x * 256 + threadIdx.x;   // 32768
  int n = idx >> 8, k = idx & 255;
  Wt[idx] = f2b(W[k * HIDN + n]);
}

// ---- fp32 X -> bf16 hi + bf16 lo (split for 3-product MFMA) ---------------
__global__ __launch_bounds__(256) void k_split2(const float* __restrict__ X,
                                                unsigned short* __restrict__ Xh,
                                                unsigned short* __restrict__ Xl) {
  long i = ((long)blockIdx.x * 256 + threadIdx.x) * 4;
  float4 v = *(const float4*)(X + i);
  ushort4 h, l;
  h.x = f2b(v.x); l.x = f2b(v.x - b2f(h.x));
  h.y = f2b(v.y); l.y = f2b(v.y - b2f(h.y));
  h.z = f2b(v.z); l.z = f2b(v.z - b2f(h.z));
  h.w = f2b(v.w); l.w = f2b(v.w - b2f(h.w));
  *(ushort4*)(Xh + i) = h;
  *(ushort4*)(Xl + i) = l;
}

// ---------------- fp32 [R][C] -> bf16 [C][R] transpose ----------------------
__global__ __launch_bounds__(256) void k_transp(const float* __restrict__ X,
                                                unsigned short* __restrict__ Xt,
                                                int R, int C) {
  __shared__ float tile[64][65];
  long bb = blockIdx.z;
  const float* Xb = X + bb * (long)R * C;
  unsigned short* Xtb = Xt + bb * (long)R * C;
  int r0 = blockIdx.y * 64, c0 = blockIdx.x * 64;
  int t = threadIdx.x;
  int tr = t >> 4, tc4 = (t & 15) * 4;
#pragma unroll
  for (int p = 0; p < 4; ++p) {
    float4 v = *(const float4*)(Xb + (long)(r0 + tr + p * 16) * C + c0 + tc4);
    tile[tr + p * 16][tc4 + 0] = v.x; tile[tr + p * 16][tc4 + 1] = v.y;
    tile[tr + p * 16][tc4 + 2] = v.z; tile[tr + p * 16][tc4 + 3] = v.w;
  }
  __syncthreads();
  int jj = t >> 2, i0 = (t & 3) * 16;
  unsigned short* orow = Xtb + (long)(c0 + jj) * R + r0 + i0;
#pragma unroll
  for (int q = 0; q < 16; ++q) orow[q] = f2b(tile[i0 + q][jj]);
}

// ---- scale-transpose-cast: Bg[b][n][j] = bf16(d[b*1024+j]*XW[b][j][n]) -----
template<int SPLIT>
__global__ __launch_bounds__(256) void k_stc(const float* __restrict__ XW,
                                             const float* __restrict__ dvv,
                                             unsigned short* __restrict__ Bh,
                                             unsigned short* __restrict__ Bl,
                                             int F) {
  __shared__ float tile[64][65];
  __shared__ float dl[64];
  int bz = blockIdx.z;
  const float* Xb = XW + (long)bz * NN * F;
  int j0 = blockIdx.x * 64;   // node dim
  int n0 = blockIdx.y * 64;   // feature dim
  int t = threadIdx.x;
  int tr = t >> 4, tc4 = (t & 15) * 4;
#pragma unroll
  for (int p = 0; p < 4; ++p) {
    float4 v = *(const float4*)(Xb + (long)(j0 + tr + p * 16) * F + n0 + tc4);
    tile[tr + p * 16][tc4 + 0] = v.x; tile[tr + p * 16][tc4 + 1] = v.y;
    tile[tr + p * 16][tc4 + 2] = v.z; tile[tr + p * 16][tc4 + 3] = v.w;
  }
  if (t < 64) dl[t] = dvv[(bz << 10) + j0 + t];
  __syncthreads();
  int nn = t >> 2, i0 = (t & 3) * 16;
  long obase = ((long)bz * F + n0 + nn) * NN + j0 + i0;
#pragma unroll
  for (int q = 0; q < 16; ++q) {
    float v = tile[i0 + q][nn] * dl[i0 + q];
    unsigned short h = f2b(v);
    Bh[obase + q] = h;
    if (SPLIT) Bl[obase + q] = f2b(v - b2f(h));
  }
}

// ---------------- bf16 NT MFMA GEMM: C[m,n] = sum_k A[m,k]*B[n,k] -----------
template<int WF32, int WBF>
__global__ __launch_bounds__(256) void k_mfma_nt(
    const unsigned short* __restrict__ A, const unsigned short* __restrict__ B,
    float* __restrict__ Cf, unsigned short* __restrict__ Cb,
    unsigned short* __restrict__ Cb2,
    int K, int ldA, int ldB, int ldC, long sA, long sB, long sC) {
  __shared__ unsigned short As[128 * 32];
  __shared__ unsigned short Bs[128 * 32];
  int bz = blockIdx.z;
  A += bz * sA; B += bz * sB;
  int m0 = blockIdx.y * 128, n0 = blockIdx.x * 128;
  int tid = threadIdx.x, lane = tid & 63, w = tid >> 6;
  int wr = w >> 1, wc = w & 1;
  facc4 acc[4][4];
#pragma unroll
  for (int i = 0; i < 4; ++i)
#pragma unroll
    for (int j = 0; j < 4; ++j)
#pragma unroll
      for (int q = 0; q < 4; ++q) acc[i][j][q] = 0.f;

  int rA0 = w * 16 + (lane >> 2);
  int kslot = lane & 3;

  for (int k0 = 0; k0 < K; k0 += 32) {
#pragma unroll
    for (int i = 0; i < 2; ++i) {
      int row = i * 64 + rA0;
      int ks = (kslot ^ (row & 3)) << 3;   // pre-swizzled global source
      GLOAD16(A + (long)(m0 + row) * ldA + k0 + ks, As + (i * 64 + w * 16) * 32);
      GLOAD16(B + (long)(n0 + row) * ldB + k0 + ks, Bs + (i * 64 + w * 16) * 32);
    }
    __syncthreads();
    bfrag8 af[4], bfr[4];
#pragma unroll
    for (int mi = 0; mi < 4; ++mi) {
      int row = wr * 64 + mi * 16 + (lane & 15);
      int sl = (((lane >> 4) ^ (row & 3)) << 3);   // swizzled read
      af[mi] = *(const bfrag8*)(As + row * 32 + sl);
    }
#pragma unroll
    for (int ni = 0; ni < 4; ++ni) {
      int row = wc * 64 + ni * 16 + (lane & 15);
      int sl = (((lane >> 4) ^ (row & 3)) << 3);
      bfr[ni] = *(const bfrag8*)(Bs + row * 32 + sl);
    }
#pragma unroll
    for (int mi = 0; mi < 4; ++mi)
#pragma unroll
      for (int ni = 0; ni < 4; ++ni)
        acc[mi][ni] = __builtin_amdgcn_mfma_f32_16x16x32_bf16(
            af[mi], bfr[ni], acc[mi][ni], 0, 0, 0);
    __syncthreads();
  }
  if (WF32) Cf += bz * sC;
  if (WBF) Cb += bz * sC;
  if (WBF == 2) Cb2 += bz * sC;
#pragma unroll
  for (int mi = 0; mi < 4; ++mi) {
    int rowb = m0 + wr * 64 + mi * 16 + ((lane >> 4) << 2);
#pragma unroll
    for (int ni = 0; ni < 4; ++ni) {
      int col = n0 + wc * 64 + ni * 16 + (lane & 15);
#pragma unroll
      for (int q = 0; q < 4; ++q) {
        long off = (long)(rowb + q) * ldC + col;
        float v = acc[mi][ni][q];
        if (WF32) Cf[off] = v;
        if (WBF == 1) Cb[off] = f2b(v);
        if (WBF == 2) {
          unsigned short h = f2b(v);
          Cb[off] = h;
          Cb2[off] = f2b(v - b2f(h));
        }
      }
    }
  }
}

// ---- GCN MFMA: x = d_m*(sum_k A[m,k]*B[n,k] + d_m*XW[m,n]) + bias[n] -------
template<int SPLIT, int RELU>
__global__ __launch_bounds__(256) void k_mfma_gcn(
    const unsigned short* __restrict__ Ah, const unsigned short* __restrict__ Al,
    const unsigned short* __restrict__ Bh, const unsigned short* __restrict__ Bl,
    const float* __restrict__ dvv, const float* __restrict__ XW,
    const float* __restrict__ bias, float* __restrict__ Cf, int F) {
  __shared__ unsigned short AsH[128 * 32], BsH[128 * 32];
  __shared__ unsigned short AsL[SPLIT ? 128 * 32 : 16], BsL[SPLIT ? 128 * 32 : 16];
  int bz = blockIdx.z;
  const unsigned short* Ahb = Ah + (long)bz * NN * NN;
  const unsigned short* Alb = SPLIT ? Al + (long)bz * NN * NN : nullptr;
  const unsigned short* Bhb = Bh + (long)bz * F * NN;
  const unsigned short* Blb = SPLIT ? Bl + (long)bz * F * NN : nullptr;
  int m0 = blockIdx.y * 128, n0 = blockIdx.x * 128;
  int tid = threadIdx.x, lane = tid & 63, w = tid >> 6;
  int wr = w >> 1, wc = w & 1;
  facc4 acc[4][4];
#pragma unroll
  for (int i = 0; i < 4; ++i)
#pragma unroll
    for (int j = 0; j < 4; ++j)
#pragma unroll
      for (int q = 0; q < 4; ++q) acc[i][j][q] = 0.f;

  int rA0 = w * 16 + (lane >> 2);
  int kslot = lane & 3;

  for (int k0 = 0; k0 < NN; k0 += 32) {
#pragma unroll
    for (int i = 0; i < 2; ++i) {
      int row = i * 64 + rA0;
      int ks = (kslot ^ (row & 3)) << 3;
      int ld = (i * 64 + w * 16) * 32;
      GLOAD16(Ahb + (long)(m0 + row) * NN + k0 + ks, AsH + ld);
      GLOAD16(Bhb + (long)(n0 + row) * NN + k0 + ks, BsH + ld);
      if (SPLIT) {
        GLOAD16(Alb + (long)(m0 + row) * NN + k0 + ks, AsL + ld);
        GLOAD16(Blb + (long)(n0 + row) * NN + k0 + ks, BsL + ld);
      }
    }
    __syncthreads();
    bfrag8 afh[4], bfh[4], afl[4], bfl[4];
#pragma unroll
    for (int mi = 0; mi < 4; ++mi) {
      int row = wr * 64 + mi * 16 + (lane & 15);
      int sl = (((lane >> 4) ^ (row & 3)) << 3);
      afh[mi] = *(const bfrag8*)(AsH + row * 32 + sl);
      if (SPLIT) afl[mi] = *(const bfrag8*)(AsL + row * 32 + sl);
    }
#pragma unroll
    for (int ni = 0; ni < 4; ++ni) {
      int row = wc * 64 + ni * 16 + (lane & 15);
      int sl = (((lane >> 4) ^ (row & 3)) << 3);
      bfh[ni] = *(const bfrag8*)(BsH + row * 32 + sl);
      if (SPLIT) bfl[ni] = *(const bfrag8*)(BsL + row * 32 + sl);
    }
#pragma unroll
    for (int mi = 0; mi < 4; ++mi)
#pragma unroll
      for (int ni = 0; ni < 4; ++ni) {
        acc[mi][ni] = __builtin_amdgcn_mfma_f32_16x16x32_bf16(
            afh[mi], bfh[ni], acc[mi][ni], 0, 0, 0);
        if (SPLIT) {
          acc[mi][ni] = __builtin_amdgcn_mfma_f32_16x16x32_bf16(
              afh[mi], bfl[ni], acc[mi][ni], 0, 0, 0);
          acc[mi][ni] = __builtin_amdgcn_mfma_f32_16x16x32_bf16(
              afl[mi], bfh[ni], acc[mi][ni], 0, 0, 0);
        }
      }
    __syncthreads();
  }
  Cf += (long)bz * NN * F;
#pragma unroll
  for (int mi = 0; mi < 4; ++mi) {
    int rowb = m0 + wr * 64 + mi * 16 + ((lane >> 4) << 2);
#pragma unroll
    for (int ni = 0; ni < 4; ++ni) {
      int col = n0 + wc * 64 + ni * 16 + (lane & 15);
      float bcol = bias[col];
#pragma unroll
      for (int q = 0; q < 4; ++q) {
        float dm = dvv[(bz << 10) + rowb + q];
        float xwv = XW[((long)(bz << 10) + rowb + q) * F + col];
        float v = dm * (acc[mi][ni][q] + dm * xwv) + bcol;
        if (RELU) v = fmaxf(v, 0.f);
        Cf[(long)(rowb + q) * F + col] = v;
      }
    }
  }
}

// ---- split-bf16 3-product NT MFMA Gram + fused C^T write -------------------
__global__ __launch_bounds__(256) void k_mfma_gram(
    const unsigned short* __restrict__ Ah, const unsigned short* __restrict__ Al,
    const unsigned short* __restrict__ Bh, const unsigned short* __restrict__ Bl,
    const float* __restrict__ xx, const float* __restrict__ yy,
    float* __restrict__ Cf, float* __restrict__ Ct) {
  __shared__ unsigned short AsH[128 * 32], AsL[128 * 32];
  __shared__ unsigned short BsH[128 * 32], BsL[128 * 32];
  int bz = blockIdx.z;
  long boff = (long)bz * NN * FIN;
  Ah += boff; Al += boff; Bh += boff; Bl += boff;
  const float* xxb = xx + (bz << 10);
  const float* yyb = yy + (bz << 10);
  int m0 = blockIdx.y * 128, n0 = blockIdx.x * 128;
  int tid = threadIdx.x, lane = tid & 63, w = tid >> 6;
  int wr = w >> 1, wc = w & 1;
  facc4 acc[4][4];
#pragma unroll
  for (int i = 0; i < 4; ++i)
#pragma unroll
    for (int j = 0; j < 4; ++j)
#pragma unroll
      for (int q = 0; q < 4; ++q) acc[i][j][q] = 0.f;

  int rA0 = w * 16 + (lane >> 2);
  int kslot = lane & 3;

  for (int k0 = 0; k0 < FIN; k0 += 32) {
#pragma unroll
    for (int i = 0; i < 2; ++i) {
      int row = i * 64 + rA0;
      int ks = (kslot ^ (row & 3)) << 3;
      long ga = (long)(m0 + row) * FIN + k0 + ks;
      long gb = (long)(n0 + row) * FIN + k0 + ks;
      int ld = (i * 64 + w * 16) * 32;
      GLOAD16(Ah + ga, AsH + ld);
      GLOAD16(Al + ga, AsL + ld);
      GLOAD16(Bh + gb, BsH + ld);
      GLOAD16(Bl + gb, BsL + ld);
    }
    __syncthreads();
    bfrag8 afh[4], afl[4], bfh[4], bfl[4];
#pragma unroll
    for (int mi = 0; mi < 4; ++mi) {
      int row = wr * 64 + mi * 16 + (lane & 15);
      int sl = (((lane >> 4) ^ (row & 3)) << 3);
      afh[mi] = *(const bfrag8*)(AsH + row * 32 + sl);
      afl[mi] = *(const bfrag8*)(AsL + row * 32 + sl);
    }
#pragma unroll
    for (int ni = 0; ni < 4; ++ni) {
      int row = wc * 64 + ni * 16 + (lane & 15);
      int sl = (((lane >> 4) ^ (row & 3)) << 3);
      bfh[ni] = *(const bfrag8*)(BsH + row * 32 + sl);
      bfl[ni] = *(const bfrag8*)(BsL + row * 32 + sl);
    }
#pragma unroll
    for (int mi = 0; mi < 4; ++mi)
#pragma unroll
      for (int ni = 0; ni < 4; ++ni) {
        acc[mi][ni] = __builtin_amdgcn_mfma_f32_16x16x32_bf16(
            afh[mi], bfh[ni], acc[mi][ni], 0, 0, 0);
        acc[mi][ni] = __builtin_amdgcn_mfma_f32_16x16x32_bf16(
            afh[mi], bfl[ni], acc[mi][ni], 0, 0, 0);
        acc[mi][ni] = __builtin_amdgcn_mfma_f32_16x16x32_bf16(
            afl[mi], bfh[ni], acc[mi][ni], 0, 0, 0);
      }
    __syncthreads();
  }
  Cf += (long)bz * NN * NN;
  Ct += (long)bz * NN * NN;
#pragma unroll
  for (int mi = 0; mi < 4; ++mi) {
    int rowb = m0 + wr * 64 + mi * 16 + ((lane >> 4) << 2);
#pragma unroll
    for (int ni = 0; ni < 4; ++ni) {
      int col = n0 + wc * 64 + ni * 16 + (lane & 15);
      float yv = yyb[col];
      float4 tv;
#pragma unroll
      for (int q = 0; q < 4; ++q) {
        float v = xxb[rowb + q] + yv - 2.f * acc[mi][ni][q];
        Cf[(long)(rowb + q) * NN + col] = v;
        ((float*)&tv)[q] = v;
      }
      *(float4*)(Ct + (long)col * NN + rowb) = tv;   // transposed write
    }
  }
}

// ---------------- s0 = cx @ Watt  (per-row dot, HID=128) --------------------
__global__ __launch_bounds__(256) void k_rowdot(const float* __restrict__ X,
                                                const float* __restrict__ w,
                                                float* __restrict__ out) {
  int t = threadIdx.x; int lane = t & 63; int wv = t >> 6;
  int row = blockIdx.x * 4 + wv;
  const float* xr = X + (long)row * HIDN;
  float s = xr[lane] * w[lane] + xr[lane + 64] * w[lane + 64];
  s = wred_sum(s);
  if (lane == 0) out[row] = s;
}

// ---- alpha (4 rows/block) = sigmoid((gcn_norm(adj) @ s0 + batt)^2) ---------
__global__ __launch_bounds__(256) void k_alpha4(const float* __restrict__ adj,
                                                const float* __restrict__ dv,
                                                const float* __restrict__ s0,
                                                const float* __restrict__ batt,
                                                float* __restrict__ alpha) {
  int r0 = blockIdx.x << 2; int b = r0 >> 10; int i0 = r0 & (NN - 1);
  int t = threadIdx.x, lane = t & 63, wv = t >> 6;
  float4 d4 = ((const float4*)(dv + (b << 10)))[t];
  float4 s4 = ((const float4*)(s0 + (b << 10)))[t];
  float w4[4];
  w4[0] = d4.x * s4.x; w4[1] = d4.y * s4.y; w4[2] = d4.z * s4.z; w4[3] = d4.w * s4.w;
  __shared__ float sm[4][4];
#pragma unroll
  for (int r = 0; r < 4; ++r) {
    float4 a4 = ((const float4*)(adj + (long)(r0 + r) * NN))[t];
    float dot = a4.x * w4[0] + a4.y * w4[1] + a4.z * w4[2] + a4.w * w4[3];
    int i = i0 + r;
    if ((i >> 2) == t) dot += w4[i & 3];   // +I diagonal
    dot = wred_sum(dot);
    if (lane == 0) sm[wv][r] = dot;
  }
  __syncthreads();
  if (t < 4) {
    float dot = sm[0][t] + sm[1][t] + sm[2][t] + sm[3][t];
    float tt = dv[r0 + t] * dot + batt[0];
    alpha[r0 + t] = 1.f / (1.f + __expf(-tt * tt));
  }
}

// ---------------- per-batch k-th largest via bitonic sort -------------------
__global__ __launch_bounds__(512) void k_topk(const float* __restrict__ alpha,
                                              float* __restrict__ cut) {
  __shared__ float smv[NN];
  int b = blockIdx.x; int t = threadIdx.x;
  smv[t] = alpha[(b << 10) + t];
  smv[t + 512] = alpha[(b << 10) + t + 512];
  __syncthreads();
  for (int k2 = 2; k2 <= NN; k2 <<= 1) {
    for (int j2 = k2 >> 1; j2 > 0; j2 >>= 1) {
      int i = ((t / j2) * (j2 << 1)) + (t % j2);
      int ixj = i + j2;
      bool up = ((i & k2) == 0);
      float a = smv[i], c = smv[ixj];
      if ((a > c) == up) { smv[i] = c; smv[ixj] = a; }
      __syncthreads();
    }
  }
  if (t == 0) cut[b] = smv[NN - KTOP];
}

// ---- S build (4 rows/block): rmask_i d_i d_j (adj+I) gate_j, row-L1 norm ---
__global__ __launch_bounds__(256) void k_sbuild4(const float* __restrict__ adj,
                                                 const float* __restrict__ dv,
                                                 const float* __restrict__ rm,
                                                 const float* __restrict__ alpha,
                                                 const float* __restrict__ cut,
                                                 float* __restrict__ S) {
  int r0 = blockIdx.x << 2; int b = r0 >> 10; int i0 = r0 & (NN - 1);
  int t = threadIdx.x, lane = t & 63, wv = t >> 6;
  float cb = cut[b];
  float4 d4 = ((const float4*)(dv + (b << 10)))[t];
  float4 al4 = ((const float4*)(alpha + (b << 10)))[t];
  float4 dg;
  dg.x = d4.x * fmaxf(al4.x + 1e-7f - cb, 0.f);
  dg.y = d4.y * fmaxf(al4.y + 1e-7f - cb, 0.f);
  dg.z = d4.z * fmaxf(al4.z + 1e-7f - cb, 0.f);
  dg.w = d4.w * fmaxf(al4.w + 1e-7f - cb, 0.f);
  __shared__ float sm[4][4];
  __shared__ float sinv[4];
  float4 vals[4];
#pragma unroll
  for (int r = 0; r < 4; ++r) {
    float di = dv[r0 + r] * rm[r0 + r];
    float4 a4 = ((const float4*)(adj + (long)(r0 + r) * NN))[t];
    int i = i0 + r;
    if ((i >> 2) == t) ((float*)&a4)[i & 3] += 1.f;
    vals[r].x = di * dg.x * a4.x; vals[r].y = di * dg.y * a4.y;
    vals[r].z = di * dg.z * a4.z; vals[r].w = di * dg.w * a4.w;
    float s = (fabsf(vals[r].x) + fabsf(vals[r].y)) +
              (fabsf(vals[r].z) + fabsf(vals[r].w));
    s = wred_sum(s);
    if (lane == 0) sm[wv][r] = s;
  }
  __syncthreads();
  if (t < 4) sinv[t] = 1.f / fmaxf(sm[0][t] + sm[1][t] + sm[2][t] + sm[3][t], 1e-12f);
  __syncthreads();
#pragma unroll
  for (int r = 0; r < 4; ++r) {
    float inv = sinv[r];
    float4 o; o.x = vals[r].x * inv; o.y = vals[r].y * inv;
    o.z = vals[r].z * inv; o.w = vals[r].w * inv;
    ((float4*)(S + (long)(r0 + r) * NN))[t] = o;
  }
}

// ---------------- K-split fp32 GEMM (TA=0,TB=0), partials out ---------------
template<int GCN>
__global__ __launch_bounds__(256) void k_gemm_ks(
    const float* __restrict__ A, const float* __restrict__ Bm, float* __restrict__ P,
    int M, int Nn, int K, int KS, long sA, long sB,
    const float* __restrict__ dv) {
  __shared__ float As[8][132];
  __shared__ float Bs[8][132];
  int z = blockIdx.z;
  int b = z / KS, ks = z % KS;
  int KC = K / KS;
  A += (long)b * sA; Bm += (long)b * sB;
  const float* dvb = GCN ? (dv + (long)b * NN) : nullptr;
  int m0 = blockIdx.y * 128, n0 = blockIdx.x * 128;
  int tid = threadIdx.x;
  int tx = tid & 15, ty = tid >> 4;
  float acc[8][8];
#pragma unroll
  for (int i = 0; i < 8; i++)
#pragma unroll
    for (int j = 0; j < 8; j++) acc[i][j] = 0.f;

  float drow = 0.f;
  if (GCN) drow = dvb[m0 + (tid >> 1)];

  for (int k0 = ks * KC; k0 < ks * KC + KC; k0 += 8) {
    {
      int r = tid >> 1, c4 = (tid & 1) * 4;
      float4 av = *(const float4*)(A + (long)(m0 + r) * K + k0 + c4);
      float a4[4] = {av.x, av.y, av.z, av.w};
      if (GCN) {
#pragma unroll
        for (int q = 0; q < 4; ++q) {
          int gj = k0 + c4 + q;
          float val = a4[q] + ((m0 + r) == gj ? 1.f : 0.f);
          a4[q] = drow * dvb[gj] * val;
        }
      }
      As[c4 + 0][r] = a4[0]; As[c4 + 1][r] = a4[1];
      As[c4 + 2][r] = a4[2]; As[c4 + 3][r] = a4[3];
    }
    {
      int kr = tid >> 5, c4 = (tid & 31) * 4;
      float4 bv = *(const float4*)(Bm + (long)(k0 + kr) * Nn + n0 + c4);
      *(float4*)&Bs[kr][c4] = bv;
    }
    __syncthreads();
#pragma unroll
    for (int k = 0; k < 8; ++k) {
      float av[8], bv[8];
      *(float4*)&av[0] = *(const float4*)&As[k][ty * 8];
      *(float4*)&av[4] = *(const float4*)&As[k][ty * 8 + 4];
      *(float4*)&bv[0] = *(const float4*)&Bs[k][tx * 8];
      *(float4*)&bv[4] = *(const float4*)&Bs[k][tx * 8 + 4];
#pragma unroll
      for (int i = 0; i < 8; i++)
#pragma unroll
        for (int j = 0; j < 8; j++)
          acc[i][j] = fmaf(av[i], bv[j], acc[i][j]);
    }
    __syncthreads();
  }
  float* Pz = P + (long)z * M * Nn;
#pragma unroll
  for (int i = 0; i < 8; ++i) {
    int m = m0 + ty * 8 + i;
    float* prow = Pz + (long)m * Nn + n0 + tx * 8;
    *(float4*)&prow[0] = *(float4*)&acc[i][0];
    *(float4*)&prow[4] = *(float4*)&acc[i][4];
  }
}

// ---------------- reduce K-split partials (+bias, +relu) --------------------
template<int RELU, int BIAS>
__global__ __launch_bounds__(256) void k_red_bias(
    const float* __restrict__ P, const float* __restrict__ bias,
    float* __restrict__ out, int Nn, int KS, long chunk) {
  long u = ((long)blockIdx.x * 256 + threadIdx.x) * 4;
  long b = u / chunk; long rem = u % chunk;
  const float* p = P + b * KS * chunk + rem;
  float4 s = *(const float4*)p;
  for (int k = 1; k < KS; ++k) {
    float4 q = *(const float4*)(p + (long)k * chunk);
    s.x += q.x; s.y += q.y; s.z += q.z; s.w += q.w;
  }
  if (BIAS) {
    int n = (int)(rem % Nn);
    s.x += bias[n]; s.y += bias[n + 1]; s.z += bias[n + 2]; s.w += bias[n + 3];
  }
  if (RELU) {
    s.x = fmaxf(s.x, 0.f); s.y = fmaxf(s.y, 0.f);
    s.z = fmaxf(s.z, 0.f); s.w = fmaxf(s.w, 0.f);
  }
  *(float4*)(out + u) = s;
}

// ---------------- column mean over nodes ------------------------------------
__global__ __launch_bounds__(256) void k_colmean(const float* __restrict__ X, int Fd,
                                                 float* __restrict__ out) {
  int nb = Fd >> 6;
  int b = blockIdx.x / nb; int f0 = (blockIdx.x % nb) << 6;
  int t = threadIdx.x;
  int f = f0 + (t & 63); int rc = t >> 6;
  const float* xb = X + (long)b * NN * Fd;
  float s = 0.f;
  for (int i = rc * 256; i < rc * 256 + 256; ++i) s += xb[(long)i * Fd + f];
  __shared__ float sm[256];
  sm[t] = s; __syncthreads();
  if (t < 64) out[b * Fd + f] = (sm[t] + sm[t + 64] + sm[t + 128] + sm[t + 192]) * (1.f / NN);
}

// ---------------- squared row norms -----------------------------------------
__global__ __launch_bounds__(256) void k_sqnorm(const float* __restrict__ X, int Fd,
                                                float* __restrict__ out) {
  int t = threadIdx.x; int lane = t & 63; int wv = t >> 6;
  int row = blockIdx.x * 4 + wv;
  const float* xr = X + (long)row * Fd;
  float s = 0.f;
  for (int f = lane; f < Fd; f += 64) { float v = xr[f]; s = fmaf(v, v, s); }
  s = wred_sum(s);
  if (lane == 0) out[row] = s;
}

// ======================= persistent register-resident Sinkhorn ==============
// Fence-free sync: data via sc0/sc1 write-through stores + in-asm vmcnt(0);
// flags via RELAXED agent atomics (no buffer_inv / buffer_wbl2 cache flushes).
// Lane owns 64 interleaved cols (col4 = k*16+jc) of one row of C and C^T in
// VGPRs, pre-scaled by 1/eps. Dual vector staged to LDS once per pass.

static __device__ __forceinline__ float4 load_cohere4(const float* p) {
  float4 v;
  asm volatile("global_load_dwordx4 %0, %1, off sc0 sc1\n\ts_waitcnt vmcnt(0)"
               : "=v"(v) : "v"(p) : "memory");
  return v;
}
static __device__ __forceinline__ float load_cohere1(const float* p) {
  float v;
  asm volatile("global_load_dword %0, %1, off sc0 sc1\n\ts_waitcnt vmcnt(0)"
               : "=v"(v) : "v"(p) : "memory");
  return v;
}
static __device__ __forceinline__ void store_cohere1(float* p, float v) {
  asm volatile("global_store_dword %0, %1, off sc0 sc1\n\ts_waitcnt vmcnt(0)"
               :: "v"(p), "v"(v) : "memory");
}

static __device__ __forceinline__ void stage_vec(float* __restrict__ vls,
                                                 const float* __restrict__ src,
                                                 int t) {
  if (t < 256) {
    float4 v = load_cohere4(src + t * 4);
    *(float4*)(vls + t * 4) = v;
  }
  __syncthreads();
}

static __device__ __forceinline__ void group_bar(int* __restrict__ slots,
                                                 int bid, int grp, int t, int g1) {
  __syncthreads();   // all waves' data stores done (vmcnt drained in-asm)
  if (t == 0)
    __hip_atomic_store(&slots[bid * 16], g1, __ATOMIC_RELAXED,
                       __HIP_MEMORY_SCOPE_AGENT);
  if (t < 32) {
    int idx = ((grp << 5) + t) * 16;
    int spin = 0;
    while (__hip_atomic_load(&slots[idx], __ATOMIC_RELAXED,
                             __HIP_MEMORY_SCOPE_AGENT) < g1) {
      if (++spin > (1 << 20)) break;
      __builtin_amdgcn_s_sleep(1);
    }
  }
  __syncthreads();
}

// One LSE half-pass for this lane's interleaved row slice.
template<int LOSS>
static __device__ __forceinline__ void pass_reg(const float4 (&Cr)[16],
    const float* __restrict__ vls, float* __restrict__ uout,
    int jc, int row, float* __restrict__ lossacc) {
  float mx = -3.0e38f;
#pragma unroll
  for (int k = 0; k < 16; ++k) {
    float4 v4 = *(const float4*)(vls + (k * 16 + jc) * 4);
    float ax = v4.x - Cr[k].x, ay = v4.y - Cr[k].y;
    float az = v4.z - Cr[k].z, aw = v4.w - Cr[k].w;
    mx = fmaxf(mx, fmaxf(fmaxf(ax, ay), fmaxf(az, aw)));
  }
#pragma unroll
  for (int m = 1; m <= 8; m <<= 1) mx = fmaxf(mx, __shfl_xor(mx, m));
  float ls = 0.f, ld = 0.f;
#pragma unroll
  for (int k = 0; k < 16; ++k) {
    float4 v4 = *(const float4*)(vls + (k * 16 + jc) * 4);
    float e;
    e = __expf(v4.x - Cr[k].x - mx); ls += e; if (LOSS) ld = fmaf(e, Cr[k].x, ld);
    e = __expf(v4.y - Cr[k].y - mx); ls += e; if (LOSS) ld = fmaf(e, Cr[k].y, ld);
    e = __expf(v4.z - Cr[k].z - mx); ls += e; if (LOSS) ld = fmaf(e, Cr[k].z, ld);
    e = __expf(v4.w - Cr[k].w - mx); ls += e; if (LOSS) ld = fmaf(e, Cr[k].w, ld);
  }
#pragma unroll
  for (int m = 1; m <= 8; m <<= 1) {
    ls += __shfl_xor(ls, m);
    if (LOSS) ld += __shfl_xor(ld, m);
  }
  if (jc == 0) {
    float uval = LOG_MU - (mx + __logf(ls));   // scaled dual u/eps
    store_cohere1(uout + row, uval);
    if (LOSS) *lossacc += (ld / ls) * (1.0f / 1024.0f);
  }
}

__global__ __launch_bounds__(512, 2) void k_sink_reg(
    const float* __restrict__ Cm, const float* __restrict__ Ct,
    float* __restrict__ uvv, float* __restrict__ vvv,
    float* __restrict__ part, float* __restrict__ oloss,
    int* __restrict__ slots1, int* __restrict__ slots2) {
  int bid = blockIdx.x, t = threadIdx.x, lane = t & 63, wvi = t >> 6;
  int jc = lane & 15;
  int row = bid * 32 + wvi * 4 + (lane >> 4);
  int b = bid >> 5;
  __shared__ float vls[1024];
  float4 Creg[16], Ctreg[16];
  {
    const float4* cp = (const float4*)(Cm + (long)row * NN);
    const float4* tp = (const float4*)(Ct + (long)row * NN);
#pragma unroll
    for (int k = 0; k < 16; ++k) {
      float4 c = cp[k * 16 + jc], ct = tp[k * 16 + jc];
      Creg[k].x = c.x * INV_EPS;  Creg[k].y = c.y * INV_EPS;
      Creg[k].z = c.z * INV_EPS;  Creg[k].w = c.w * INV_EPS;
      Ctreg[k].x = ct.x * INV_EPS; Ctreg[k].y = ct.y * INV_EPS;
      Ctreg[k].z = ct.z * INV_EPS; Ctreg[k].w = ct.w * INV_EPS;
    }
  }
  const float* ub = uvv + (b << 10);
  const float* vb = vvv + (b << 10);
  float lossacc = 0.f;
  int g1 = 1;
  for (int it = 0; it < NITER; ++it) {
    stage_vec(vls, vb, t);                                 // v -> LDS
    pass_reg<0>(Creg, vls, uvv, jc, row, nullptr);         // u update
    group_bar(slots1, bid, b, t, g1); ++g1;
    stage_vec(vls, ub, t);                                 // u -> LDS
    if (it < NITER - 1) {
      pass_reg<0>(Ctreg, vls, vvv, jc, row, nullptr);      // v update
      group_bar(slots1, bid, b, t, g1); ++g1;
    } else {
      pass_reg<1>(Ctreg, vls, vvv, jc, row, &lossacc);     // v + fused loss
    }
  }
  // per-block loss partial
  float s = wred_sum(lossacc);
  __shared__ float lsm[8];
  if (lane == 0) lsm[wvi] = s;
  __syncthreads();
  if (t == 0) {
    float ps = 0.f;
#pragma unroll
    for (int i = 0; i < 8; ++i) ps += lsm[i];
    store_cohere1(part + bid, ps);
    __hip_atomic_store(&slots2[bid * 16], 1, __ATOMIC_RELAXED,
                       __HIP_MEMORY_SCOPE_AGENT);
  }
  if (bid == 0) {
    if (t < SNB) {
      int spin = 0;
      while (__hip_atomic_load(&slots2[t * 16], __ATOMIC_RELAXED,
                               __HIP_MEMORY_SCOPE_AGENT) < 1) {
        if (++spin > (1 << 20)) break;
        __builtin_amdgcn_s_sleep(1);
      }
    }
    __syncthreads();
    float s2 = 0.f;
    if (t < SNB) s2 = load_cohere1(part + t);
    s2 = wred_sum(s2);
    __shared__ float sm2[8];
    if (lane == 0) sm2[wvi] = s2;
    __syncthreads();
    if (t == 0) {
      float tot = 0.f;
#pragma unroll
      for (int i = 0; i < 8; ++i) tot += sm2[i];
      oloss[0] = tot * EPS_S;   // undo the 1/eps scaling of C' in ld
    }
  }
}

extern "C" void kernel_launch(void* const* d_in, const int* in_sizes, int n_in,
                              void* d_out, int out_size, void* d_ws, size_t ws_size,
                              hipStream_t stream) {
  const float* x    = (const float*)d_in[0];
  const float* adj  = (const float*)d_in[1];
  const float* W1   = (const float*)d_in[3];
  const float* b1   = (const float*)d_in[4];
  const float* Watt = (const float*)d_in[5];
  const float* batt = (const float*)d_in[6];
  const float* W2   = (const float*)d_in[7];
  const float* b2   = (const float*)d_in[8];

  float* out = (float*)d_out;
  float* xs0   = out;                    // [8,128]
  float* xs1   = out + 1024;             // [8,256]
  float* oadj0 = out + 3072;             // [8,1024,1024]
  float* oadj1 = oadj0 + 8388608;
  float* oadj2 = oadj1 + 8388608;        // adj_bf scratch until adj2 written
  float* oS0   = oadj2 + 8388608;
  float* oS1   = oS0 + 8388608;
  float* oloss = oS1 + 8388608;          // [1]

  float* ws   = (float*)d_ws;
  float* wXW  = ws;                       // 2,097,152 (XW1 then XW2)
  float* wCXA = wXW + 2097152;            // 1,048,576 (x1, later emb2)
  float* wCXB = wCXA + 1048576;           // 1,048,576 (emb1)
  float* wR   = wCXB + 1048576;           // 8,388,608 (tmp_bf | P | Cmat)
  float* wX2  = wR + 8388608;             // 2,097,152 (x2)
  float* wStf = wX2 + 2097152;            // 4,194,304 (x_bf/St/Bg2/x-splits)
  float* wCxtf= wStf + 4194304;           // 524,288   (Bg1 / cxt)
  float* wCt  = wCxtf + 524288;           // 8,388,608 (a2h+a2l, then C^T)
  float* smb  = wCt + 8388608;

  unsigned short* tmp_bf = (unsigned short*)wR;                 // 16.7MB half
  unsigned short* a2h    = (unsigned short*)wCt;                // 8,388,608 sh
  unsigned short* a2l    = a2h + 8388608;                       // 8,388,608 sh
  unsigned short* adj_bf = (unsigned short*)oadj2;
  unsigned short* St     = (unsigned short*)wStf;
  unsigned short* cxt    = (unsigned short*)wCxtf;
  unsigned short* x_bf   = (unsigned short*)wStf;               // pre-coarsen
  unsigned short* Bg1    = (unsigned short*)wCxtf;
  unsigned short* Bg2h   = (unsigned short*)wStf;               // post-adj2
  unsigned short* Bg2l   = (unsigned short*)(wStf + 2097152);
  unsigned short* xh  = (unsigned short*)wStf;                  // sinkhorn phase
  unsigned short* xl  = xh + 2097152;
  unsigned short* x2h = xh + 4194304;
  unsigned short* x2l = xh + 6291456;
  float* Cmat = wR;
  float* d0 = smb;            float* rm0 = smb + 8192;
  float* d1 = smb + 16384;    float* rm1 = smb + 24576;
  float* d2 = smb + 32768;    float* rm2 = smb + 40960;
  float* s0v = smb + 49152;   float* alp = smb + 57344;
  float* xxv = smb + 65536;   float* yyv = smb + 73728;
  float* uv  = smb + 81920;   float* vv  = smb + 90112;   // contiguous
  float* cutv = smb + 98304;  float* part = smb + 98368;  // 256
  unsigned short* W1t = (unsigned short*)(smb + 98624);    // 32768 shorts
  int* ibar = (int*)(smb + 115008);
  int* slots1 = ibar;                 // 256*16 ints
  int* slots2 = ibar + 4096;          // 256*16 ints

  // rowstats on adj + fused bf16 copy (into oadj2 region) + fp32 copy (oadj0)
  k_rowstats4<1, 1><<<2048, 256, 0, stream>>>(adj, d0, rm0, adj_bf, oadj0);

  // ---- GCN1 (MFMA): x1 = relu(d*(adj_bf @ (d.*XW1) + d*XW1_diag) + b1) ----
  k_f2b<<<2048, 256, 0, stream>>>(x, x_bf);
  k_w1t<<<128, 256, 0, stream>>>(W1, W1t);
  k_mfma_nt<1, 0><<<dim3(1, 64, 1), 256, 0, stream>>>(x_bf, W1t, wXW, nullptr,
      nullptr, 256, 256, 256, 128, 0L, 0L, 0L);
  k_stc<0><<<dim3(16, 2, 8), 256, 0, stream>>>(wXW, d0, Bg1, nullptr, HIDN);
  k_mfma_gcn<0, 1><<<dim3(1, 8, 8), 256, 0, stream>>>(adj_bf, nullptr, Bg1,
      nullptr, d0, wXW, b1, wCXA, HIDN);
  k_colmean<<<16, 256, 0, stream>>>(wCXA, HIDN, xs0);

  // ---- coarsen layer 1 ----
  k_rowdot<<<2048, 256, 0, stream>>>(wCXA, Watt, s0v);
  k_alpha4<<<2048, 256, 0, stream>>>(adj, d0, s0v, batt, alp);
  k_topk<<<8, 512, 0, stream>>>(alp, cutv);
  k_sbuild4<<<2048, 256, 0, stream>>>(adj, d0, rm0, alp, cutv, oS0);
  k_transp<<<dim3(16, 16, 8), 256, 0, stream>>>(oS0, St, 1024, 1024);
  k_transp<<<dim3(2, 16, 8), 256, 0, stream>>>(wCXA, cxt, 1024, 128);
  k_mfma_nt<1, 0><<<dim3(1, 8, 8), 256, 0, stream>>>(St, cxt, wCXB, nullptr,
      nullptr, 1024, 1024, 1024, 128, 1048576L, 131072L, 131072L);
  k_mfma_nt<0, 1><<<dim3(8, 8, 8), 256, 0, stream>>>(St, adj_bf, nullptr, tmp_bf,
      nullptr, 1024, 1024, 1024, 1024, 1048576L, 1048576L, 1048576L);
  k_mfma_nt<1, 1><<<dim3(8, 8, 8), 256, 0, stream>>>(tmp_bf, St, oadj1, adj_bf,
      nullptr, 1024, 1024, 1024, 1024, 1048576L, 1048576L, 1048576L);
  k_rowstats4<0, 0><<<2048, 256, 0, stream>>>(oadj1, d1, rm1, nullptr, nullptr);

  // ---- coarsen layer 2 ----
  k_rowdot<<<2048, 256, 0, stream>>>(wCXB, Watt, s0v);
  k_alpha4<<<2048, 256, 0, stream>>>(oadj1, d1, s0v, batt, alp);
  k_topk<<<8, 512, 0, stream>>>(alp, cutv);
  k_sbuild4<<<2048, 256, 0, stream>>>(oadj1, d1, rm1, alp, cutv, oS1);
  k_transp<<<dim3(16, 16, 8), 256, 0, stream>>>(oS1, St, 1024, 1024);
  k_transp<<<dim3(2, 16, 8), 256, 0, stream>>>(wCXB, cxt, 1024, 128);
  k_mfma_nt<1, 0><<<dim3(1, 8, 8), 256, 0, stream>>>(St, cxt, wCXA, nullptr,
      nullptr, 1024, 1024, 1024, 128, 1048576L, 131072L, 131072L);
  k_mfma_nt<0, 1><<<dim3(8, 8, 8), 256, 0, stream>>>(St, adj_bf, nullptr, tmp_bf,
      nullptr, 1024, 1024, 1024, 1024, 1048576L, 1048576L, 1048576L);
  // adj2 -> fp32 output + hi/lo bf16 pair (in wCt region) for split final GCN
  k_mfma_nt<1, 2><<<dim3(8, 8, 8), 256, 0, stream>>>(tmp_bf, St, oadj2, a2h,
      a2l, 1024, 1024, 1024, 1024, 1048576L, 1048576L, 1048576L);
  k_rowstats4<0, 0><<<2048, 256, 0, stream>>>(oadj2, d2, rm2, nullptr, nullptr);

  // ---- final GCN (split-bf16 MFMA): x2 = d*(A2@(d.*XW2) + d*XW2_diag) + b2 --
  k_gemm_ks<0><<<dim3(2, 64, 2), 256, 0, stream>>>(wCXA, W2, wR, 8192, FIN, HIDN,
      2, 0L, 0L, nullptr);   // P partials in wR first half (tmp_bf dead)
  k_red_bias<0, 0><<<2048, 256, 0, stream>>>(wR, nullptr, wXW, FIN, 2, 2097152L);
  k_stc<1><<<dim3(16, 4, 8), 256, 0, stream>>>(wXW, d2, Bg2h, Bg2l, FIN);
  k_mfma_gcn<1, 0><<<dim3(2, 8, 8), 256, 0, stream>>>(a2h, a2l, Bg2h, Bg2l,
      d2, wXW, b2, wX2, FIN);
  k_colmean<<<32, 256, 0, stream>>>(wX2, FIN, xs1);

  // ---- Sinkhorn: C via split-bf16 MFMA Gram (+fused C^T), reg-resident solve
  k_sqnorm<<<2048, 256, 0, stream>>>(x, FIN, xxv);
  k_sqnorm<<<2048, 256, 0, stream>>>(wX2, FIN, yyv);
  k_split2<<<2048, 256, 0, stream>>>(x, xh, xl);
  k_split2<<<2048, 256, 0, stream>>>(wX2, x2h, x2l);
  k_mfma_gram<<<dim3(8, 8, 8), 256, 0, stream>>>(xh, xl, x2h, x2l, xxv, yyv,
      Cmat, wCt);
  hipMemsetAsync(uv, 0, (size_t)2 * 8192 * 4, stream);
  hipMemsetAsync(ibar, 0, (size_t)8192 * 4, stream);
  k_sink_reg<<<SNB, 512, 0, stream>>>(Cmat, wCt, uv, vv, part, oloss,
                                      slots1, slots2);
}

// Round 9
// 743.316 us; speedup vs baseline: 2.2651x; 1.0080x over previous
//
#include <hip/hip_runtime.h>
#include <math.h>

// Problem constants (fixed by the reference)
#define BN   8
#define NN   1024
#define FIN  256
#define HIDN 128
#define KTOP 513          // int(1024*0.5)+1
#define NITER 20          // opt_epochs in setup_inputs
#define EPS_S 0.01f
#define INV_EPS 100.0f
#define LOG_MU (-6.9314718055994531f)   // -log(1024)
#define SNB 256           // blocks in persistent sinkhorn kernel

typedef __attribute__((ext_vector_type(8))) short bfrag8;   // 8 bf16 (4 VGPR)
typedef __attribute__((ext_vector_type(4))) float facc4;    // MFMA accumulator

#define GLOAD16(g, l) __builtin_amdgcn_global_load_lds( \
    (const __attribute__((address_space(1))) unsigned int*)(g), \
    (__attribute__((address_space(3))) unsigned int*)(l), 16, 0, 0)

static __device__ __forceinline__ float wred_sum(float s) {
#pragma unroll
  for (int o = 32; o > 0; o >>= 1) s += __shfl_xor(s, o);
  return s;
}
static __device__ __forceinline__ unsigned short f2b(float f) {
  unsigned int u = __float_as_uint(f);
  u += 0x7fff + ((u >> 16) & 1);      // RNE
  return (unsigned short)(u >> 16);
}
static __device__ __forceinline__ float b2f(unsigned short h) {
  return __uint_as_float((unsigned int)h << 16);
}

// ---- rowstats (4 rows/block): d = rsqrt(max(rowsum+1,1)), rmask ------------
template<int WRBF, int WCOPY>
__global__ __launch_bounds__(256) void k_rowstats4(const float* __restrict__ adj,
                                                   float* __restrict__ dv,
                                                   float* __restrict__ rm,
                                                   unsigned short* __restrict__ abf,
                                                   float* __restrict__ ocopy) {
  int r0 = blockIdx.x << 2;
  int t = threadIdx.x, lane = t & 63, wv = t >> 6;
  __shared__ float sm[4][4];
#pragma unroll
  for (int r = 0; r < 4; ++r) {
    float4 v = ((const float4*)(adj + (long)(r0 + r) * NN))[t];
    if (WRBF) {
      ushort4 h; h.x = f2b(v.x); h.y = f2b(v.y); h.z = f2b(v.z); h.w = f2b(v.w);
      *(ushort4*)(abf + (long)(r0 + r) * NN + t * 4) = h;
    }
    if (WCOPY) ((float4*)(ocopy + (long)(r0 + r) * NN))[t] = v;
    float s = (v.x + v.y) + (v.z + v.w);
    s = wred_sum(s);
    if (lane == 0) sm[wv][r] = s;
  }
  __syncthreads();
  if (t < 4) {
    float tot = sm[0][t] + sm[1][t] + sm[2][t] + sm[3][t];
    dv[r0 + t] = rsqrtf(fmaxf(tot + 1.0f, 1.0f));
    rm[r0 + t] = tot > 0.0f ? 1.0f : 0.0f;
  }
}

// ---------------- fp32 -> bf16 elementwise ----------------------------------
__global__ __launch_bounds__(256) void k_f2b(const float* __restrict__ X,
                                             unsigned short* __restrict__ Y) {
  long i = ((long)blockIdx.x * 256 + threadIdx.x) * 4;
  float4 v = *(const float4*)(X + i);
  Y[i] = f2b(v.x); Y[i + 1] = f2b(v.y); Y[i + 2] = f2b(v.z); Y[i + 3] = f2b(v.w);
}

// ---- W1 [256][128] fp32 -> W1t [128][256] bf16 -----------------------------
__global__ __launch_bounds__(256) void k_w1t(const float* __restrict__ W,
                                             unsigned short* __restrict__ Wt) {
  int idx = blockIdx.x * 256 + threadIdx.x;   // 32768
  int n = idx >> 8, k = idx & 255;
  Wt[idx] = f2b(W[k * HIDN + n]);
}

// ---- fused sqnorm + hi/lo bf16 split (rows of length FIN=256) --------------
// 4 rows/block, one wave per row, float4 per lane.
__global__ __launch_bounds__(256) void k_prep(const float* __restrict__ X,
                                              unsigned short* __restrict__ Xh,
                                              unsigned short* __restrict__ Xl,
                                              float* __restrict__ sq) {
  int t = threadIdx.x, lane = t & 63, wv = t >> 6;
  int row = blockIdx.x * 4 + wv;
  long base = (long)row * FIN + lane * 4;
  float4 v = *(const float4*)(X + base);
  ushort4 h, l;
  h.x = f2b(v.x); l.x = f2b(v.x - b2f(h.x));
  h.y = f2b(v.y); l.y = f2b(v.y - b2f(h.y));
  h.z = f2b(v.z); l.z = f2b(v.z - b2f(h.z));
  h.w = f2b(v.w); l.w = f2b(v.w - b2f(h.w));
  *(ushort4*)(Xh + base) = h;
  *(ushort4*)(Xl + base) = l;
  float s = v.x * v.x + v.y * v.y + v.z * v.z + v.w * v.w;
  s = wred_sum(s);
  if (lane == 0) sq[row] = s;
}

// ---------------- fp32 [R][C] -> bf16 [C][R] transpose ----------------------
__global__ __launch_bounds__(256) void k_transp(const float* __restrict__ X,
                                                unsigned short* __restrict__ Xt,
                                                int R, int C) {
  __shared__ float tile[64][65];
  long bb = blockIdx.z;
  const float* Xb = X + bb * (long)R * C;
  unsigned short* Xtb = Xt + bb * (long)R * C;
  int r0 = blockIdx.y * 64, c0 = blockIdx.x * 64;
  int t = threadIdx.x;
  int tr = t >> 4, tc4 = (t & 15) * 4;
#pragma unroll
  for (int p = 0; p < 4; ++p) {
    float4 v = *(const float4*)(Xb + (long)(r0 + tr + p * 16) * C + c0 + tc4);
    tile[tr + p * 16][tc4 + 0] = v.x; tile[tr + p * 16][tc4 + 1] = v.y;
    tile[tr + p * 16][tc4 + 2] = v.z; tile[tr + p * 16][tc4 + 3] = v.w;
  }
  __syncthreads();
  int jj = t >> 2, i0 = (t & 3) * 16;
  unsigned short* orow = Xtb + (long)(c0 + jj) * R + r0 + i0;
#pragma unroll
  for (int q = 0; q < 16; ++q) orow[q] = f2b(tile[i0 + q][jj]);
}

// ---- scale-transpose-cast: Bg[b][n][j] = bf16(d[b*1024+j]*XW[b][j][n]) -----
template<int SPLIT>
__global__ __launch_bounds__(256) void k_stc(const float* __restrict__ XW,
                                             const float* __restrict__ dvv,
                                             unsigned short* __restrict__ Bh,
                                             unsigned short* __restrict__ Bl,
                                             int F) {
  __shared__ float tile[64][65];
  __shared__ float dl[64];
  int bz = blockIdx.z;
  const float* Xb = XW + (long)bz * NN * F;
  int j0 = blockIdx.x * 64;   // node dim
  int n0 = blockIdx.y * 64;   // feature dim
  int t = threadIdx.x;
  int tr = t >> 4, tc4 = (t & 15) * 4;
#pragma unroll
  for (int p = 0; p < 4; ++p) {
    float4 v = *(const float4*)(Xb + (long)(j0 + tr + p * 16) * F + n0 + tc4);
    tile[tr + p * 16][tc4 + 0] = v.x; tile[tr + p * 16][tc4 + 1] = v.y;
    tile[tr + p * 16][tc4 + 2] = v.z; tile[tr + p * 16][tc4 + 3] = v.w;
  }
  if (t < 64) dl[t] = dvv[(bz << 10) + j0 + t];
  __syncthreads();
  int nn = t >> 2, i0 = (t & 3) * 16;
  long obase = ((long)bz * F + n0 + nn) * NN + j0 + i0;
#pragma unroll
  for (int q = 0; q < 16; ++q) {
    float v = tile[i0 + q][nn] * dl[i0 + q];
    unsigned short h = f2b(v);
    Bh[obase + q] = h;
    if (SPLIT) Bl[obase + q] = f2b(v - b2f(h));
  }
}

// ---------------- bf16 NT MFMA GEMM: C[m,n] = sum_k A[m,k]*B[n,k] -----------
template<int WF32, int WBF>
__global__ __launch_bounds__(256) void k_mfma_nt(
    const unsigned short* __restrict__ A, const unsigned short* __restrict__ B,
    float* __restrict__ Cf, unsigned short* __restrict__ Cb,
    unsigned short* __restrict__ Cb2,
    int K, int ldA, int ldB, int ldC, long sA, long sB, long sC) {
  __shared__ unsigned short As[128 * 32];
  __shared__ unsigned short Bs[128 * 32];
  int bz = blockIdx.z;
  A += bz * sA; B += bz * sB;
  int m0 = blockIdx.y * 128, n0 = blockIdx.x * 128;
  int tid = threadIdx.x, lane = tid & 63, w = tid >> 6;
  int wr = w >> 1, wc = w & 1;
  facc4 acc[4][4];
#pragma unroll
  for (int i = 0; i < 4; ++i)
#pragma unroll
    for (int j = 0; j < 4; ++j)
#pragma unroll
      for (int q = 0; q < 4; ++q) acc[i][j][q] = 0.f;

  int rA0 = w * 16 + (lane >> 2);
  int kslot = lane & 3;

  for (int k0 = 0; k0 < K; k0 += 32) {
#pragma unroll
    for (int i = 0; i < 2; ++i) {
      int row = i * 64 + rA0;
      int ks = (kslot ^ (row & 3)) << 3;   // pre-swizzled global source
      GLOAD16(A + (long)(m0 + row) * ldA + k0 + ks, As + (i * 64 + w * 16) * 32);
      GLOAD16(B + (long)(n0 + row) * ldB + k0 + ks, Bs + (i * 64 + w * 16) * 32);
    }
    __syncthreads();
    bfrag8 af[4], bfr[4];
#pragma unroll
    for (int mi = 0; mi < 4; ++mi) {
      int row = wr * 64 + mi * 16 + (lane & 15);
      int sl = (((lane >> 4) ^ (row & 3)) << 3);   // swizzled read
      af[mi] = *(const bfrag8*)(As + row * 32 + sl);
    }
#pragma unroll
    for (int ni = 0; ni < 4; ++ni) {
      int row = wc * 64 + ni * 16 + (lane & 15);
      int sl = (((lane >> 4) ^ (row & 3)) << 3);
      bfr[ni] = *(const bfrag8*)(Bs + row * 32 + sl);
    }
#pragma unroll
    for (int mi = 0; mi < 4; ++mi)
#pragma unroll
      for (int ni = 0; ni < 4; ++ni)
        acc[mi][ni] = __builtin_amdgcn_mfma_f32_16x16x32_bf16(
            af[mi], bfr[ni], acc[mi][ni], 0, 0, 0);
    __syncthreads();
  }
  if (WF32) Cf += bz * sC;
  if (WBF) Cb += bz * sC;
  if (WBF == 2) Cb2 += bz * sC;
#pragma unroll
  for (int mi = 0; mi < 4; ++mi) {
    int rowb = m0 + wr * 64 + mi * 16 + ((lane >> 4) << 2);
#pragma unroll
    for (int ni = 0; ni < 4; ++ni) {
      int col = n0 + wc * 64 + ni * 16 + (lane & 15);
#pragma unroll
      for (int q = 0; q < 4; ++q) {
        long off = (long)(rowb + q) * ldC + col;
        float v = acc[mi][ni][q];
        if (WF32) Cf[off] = v;
        if (WBF == 1) Cb[off] = f2b(v);
        if (WBF == 2) {
          unsigned short h = f2b(v);
          Cb[off] = h;
          Cb2[off] = f2b(v - b2f(h));
        }
      }
    }
  }
}

// ---- merged coarsening GEMM: grid (9, 8, 8) --------------------------------
// bx<8 : tmp[m,n] = sum_k St[m,k]*adj_bf[n,k]  -> bf16 tmp_out (ld 1024)
// bx==8: emb[m,n] = sum_k St[m,k]*cxt[n,k]     -> fp32 emb_out (ld 128)
__global__ __launch_bounds__(256) void k_coars(
    const unsigned short* __restrict__ St, const unsigned short* __restrict__ Badj,
    const unsigned short* __restrict__ cxt,
    unsigned short* __restrict__ tmpo, float* __restrict__ embo) {
  __shared__ unsigned short As[128 * 32];
  __shared__ unsigned short Bs[128 * 32];
  int bz = blockIdx.z;
  int bx = blockIdx.x;
  int em = (bx == 8);
  const unsigned short* A = St + (long)bz * 1048576;
  const unsigned short* B = em ? (cxt + (long)bz * 131072)
                               : (Badj + (long)bz * 1048576);
  int m0 = blockIdx.y * 128, n0 = em ? 0 : bx * 128;
  int tid = threadIdx.x, lane = tid & 63, w = tid >> 6;
  int wr = w >> 1, wc = w & 1;
  facc4 acc[4][4];
#pragma unroll
  for (int i = 0; i < 4; ++i)
#pragma unroll
    for (int j = 0; j < 4; ++j)
#pragma unroll
      for (int q = 0; q < 4; ++q) acc[i][j][q] = 0.f;

  int rA0 = w * 16 + (lane >> 2);
  int kslot = lane & 3;

  for (int k0 = 0; k0 < NN; k0 += 32) {
#pragma unroll
    for (int i = 0; i < 2; ++i) {
      int row = i * 64 + rA0;
      int ks = (kslot ^ (row & 3)) << 3;
      GLOAD16(A + (long)(m0 + row) * NN + k0 + ks, As + (i * 64 + w * 16) * 32);
      GLOAD16(B + (long)(n0 + row) * NN + k0 + ks, Bs + (i * 64 + w * 16) * 32);
    }
    __syncthreads();
    bfrag8 af[4], bfr[4];
#pragma unroll
    for (int mi = 0; mi < 4; ++mi) {
      int row = wr * 64 + mi * 16 + (lane & 15);
      int sl = (((lane >> 4) ^ (row & 3)) << 3);
      af[mi] = *(const bfrag8*)(As + row * 32 + sl);
    }
#pragma unroll
    for (int ni = 0; ni < 4; ++ni) {
      int row = wc * 64 + ni * 16 + (lane & 15);
      int sl = (((lane >> 4) ^ (row & 3)) << 3);
      bfr[ni] = *(const bfrag8*)(Bs + row * 32 + sl);
    }
#pragma unroll
    for (int mi = 0; mi < 4; ++mi)
#pragma unroll
      for (int ni = 0; ni < 4; ++ni)
        acc[mi][ni] = __builtin_amdgcn_mfma_f32_16x16x32_bf16(
            af[mi], bfr[ni], acc[mi][ni], 0, 0, 0);
    __syncthreads();
  }
#pragma unroll
  for (int mi = 0; mi < 4; ++mi) {
    int rowb = m0 + wr * 64 + mi * 16 + ((lane >> 4) << 2);
#pragma unroll
    for (int ni = 0; ni < 4; ++ni) {
      int col = n0 + wc * 64 + ni * 16 + (lane & 15);
#pragma unroll
      for (int q = 0; q < 4; ++q) {
        float v = acc[mi][ni][q];
        if (em)
          embo[(long)bz * 131072 + (long)(rowb + q) * HIDN + col] = v;
        else
          tmpo[(long)bz * 1048576 + (long)(rowb + q) * NN + col] = f2b(v);
      }
    }
  }
}

// ---- GCN MFMA: x = d_m*(sum_k A[m,k]*B[n,k] + d_m*XW[m,n]) + bias[n] -------
template<int SPLIT, int RELU>
__global__ __launch_bounds__(256) void k_mfma_gcn(
    const unsigned short* __restrict__ Ah, const unsigned short* __restrict__ Al,
    const unsigned short* __restrict__ Bh, const unsigned short* __restrict__ Bl,
    const float* __restrict__ dvv, const float* __restrict__ XW,
    const float* __restrict__ bias, float* __restrict__ Cf, int F) {
  __shared__ unsigned short AsH[128 * 32], BsH[128 * 32];
  __shared__ unsigned short AsL[SPLIT ? 128 * 32 : 16], BsL[SPLIT ? 128 * 32 : 16];
  int bz = blockIdx.z;
  const unsigned short* Ahb = Ah + (long)bz * NN * NN;
  const unsigned short* Alb = SPLIT ? Al + (long)bz * NN * NN : nullptr;
  const unsigned short* Bhb = Bh + (long)bz * F * NN;
  const unsigned short* Blb = SPLIT ? Bl + (long)bz * F * NN : nullptr;
  int m0 = blockIdx.y * 128, n0 = blockIdx.x * 128;
  int tid = threadIdx.x, lane = tid & 63, w = tid >> 6;
  int wr = w >> 1, wc = w & 1;
  facc4 acc[4][4];
#pragma unroll
  for (int i = 0; i < 4; ++i)
#pragma unroll
    for (int j = 0; j < 4; ++j)
#pragma unroll
      for (int q = 0; q < 4; ++q) acc[i][j][q] = 0.f;

  int rA0 = w * 16 + (lane >> 2);
  int kslot = lane & 3;

  for (int k0 = 0; k0 < NN; k0 += 32) {
#pragma unroll
    for (int i = 0; i < 2; ++i) {
      int row = i * 64 + rA0;
      int ks = (kslot ^ (row & 3)) << 3;
      int ld = (i * 64 + w * 16) * 32;
      GLOAD16(Ahb + (long)(m0 + row) * NN + k0 + ks, AsH + ld);
      GLOAD16(Bhb + (long)(n0 + row) * NN + k0 + ks, BsH + ld);
      if (SPLIT) {
        GLOAD16(Alb + (long)(m0 + row) * NN + k0 + ks, AsL + ld);
        GLOAD16(Blb + (long)(n0 + row) * NN + k0 + ks, BsL + ld);
      }
    }
    __syncthreads();
    bfrag8 afh[4], bfh[4], afl[4], bfl[4];
#pragma unroll
    for (int mi = 0; mi < 4; ++mi) {
      int row = wr * 64 + mi * 16 + (lane & 15);
      int sl = (((lane >> 4) ^ (row & 3)) << 3);
      afh[mi] = *(const bfrag8*)(AsH + row * 32 + sl);
      if (SPLIT) afl[mi] = *(const bfrag8*)(AsL + row * 32 + sl);
    }
#pragma unroll
    for (int ni = 0; ni < 4; ++ni) {
      int row = wc * 64 + ni * 16 + (lane & 15);
      int sl = (((lane >> 4) ^ (row & 3)) << 3);
      bfh[ni] = *(const bfrag8*)(BsH + row * 32 + sl);
      if (SPLIT) bfl[ni] = *(const bfrag8*)(BsL + row * 32 + sl);
    }
#pragma unroll
    for (int mi = 0; mi < 4; ++mi)
#pragma unroll
      for (int ni = 0; ni < 4; ++ni) {
        acc[mi][ni] = __builtin_amdgcn_mfma_f32_16x16x32_bf16(
            afh[mi], bfh[ni], acc[mi][ni], 0, 0, 0);
        if (SPLIT) {
          acc[mi][ni] = __builtin_amdgcn_mfma_f32_16x16x32_bf16(
              afh[mi], bfl[ni], acc[mi][ni], 0, 0, 0);
          acc[mi][ni] = __builtin_amdgcn_mfma_f32_16x16x32_bf16(
              afl[mi], bfh[ni], acc[mi][ni], 0, 0, 0);
        }
      }
    __syncthreads();
  }
  Cf += (long)bz * NN * F;
#pragma unroll
  for (int mi = 0; mi < 4; ++mi) {
    int rowb = m0 + wr * 64 + mi * 16 + ((lane >> 4) << 2);
#pragma unroll
    for (int ni = 0; ni < 4; ++ni) {
      int col = n0 + wc * 64 + ni * 16 + (lane & 15);
      float bcol = bias[col];
#pragma unroll
      for (int q = 0; q < 4; ++q) {
        float dm = dvv[(bz << 10) + rowb + q];
        float xwv = XW[((long)(bz << 10) + rowb + q) * F + col];
        float v = dm * (acc[mi][ni][q] + dm * xwv) + bcol;
        if (RELU) v = fmaxf(v, 0.f);
        Cf[(long)(rowb + q) * F + col] = v;
      }
    }
  }
}

// ---- split-bf16 3-product NT MFMA Gram + fused C^T write -------------------
__global__ __launch_bounds__(256) void k_mfma_gram(
    const unsigned short* __restrict__ Ah, const unsigned short* __restrict__ Al,
    const unsigned short* __restrict__ Bh, const unsigned short* __restrict__ Bl,
    const float* __restrict__ xx, const float* __restrict__ yy,
    float* __restrict__ Cf, float* __restrict__ Ct) {
  __shared__ unsigned short AsH[128 * 32], AsL[128 * 32];
  __shared__ unsigned short BsH[128 * 32], BsL[128 * 32];
  int bz = blockIdx.z;
  long boff = (long)bz * NN * FIN;
  Ah += boff; Al += boff; Bh += boff; Bl += boff;
  const float* xxb = xx + (bz << 10);
  const float* yyb = yy + (bz << 10);
  int m0 = blockIdx.y * 128, n0 = blockIdx.x * 128;
  int tid = threadIdx.x, lane = tid & 63, w = tid >> 6;
  int wr = w >> 1, wc = w & 1;
  facc4 acc[4][4];
#pragma unroll
  for (int i = 0; i < 4; ++i)
#pragma unroll
    for (int j = 0; j < 4; ++j)
#pragma unroll
      for (int q = 0; q < 4; ++q) acc[i][j][q] = 0.f;

  int rA0 = w * 16 + (lane >> 2);
  int kslot = lane & 3;

  for (int k0 = 0; k0 < FIN; k0 += 32) {
#pragma unroll
    for (int i = 0; i < 2; ++i) {
      int row = i * 64 + rA0;
      int ks = (kslot ^ (row & 3)) << 3;
      long ga = (long)(m0 + row) * FIN + k0 + ks;
      long gb = (long)(n0 + row) * FIN + k0 + ks;
      int ld = (i * 64 + w * 16) * 32;
      GLOAD16(Ah + ga, AsH + ld);
      GLOAD16(Al + ga, AsL + ld);
      GLOAD16(Bh + gb, BsH + ld);
      GLOAD16(Bl + gb, BsL + ld);
    }
    __syncthreads();
    bfrag8 afh[4], afl[4], bfh[4], bfl[4];
#pragma unroll
    for (int mi = 0; mi < 4; ++mi) {
      int row = wr * 64 + mi * 16 + (lane & 15);
      int sl = (((lane >> 4) ^ (row & 3)) << 3);
      afh[mi] = *(const bfrag8*)(AsH + row * 32 + sl);
      afl[mi] = *(const bfrag8*)(AsL + row * 32 + sl);
    }
#pragma unroll
    for (int ni = 0; ni < 4; ++ni) {
      int row = wc * 64 + ni * 16 + (lane & 15);
      int sl = (((lane >> 4) ^ (row & 3)) << 3);
      bfh[ni] = *(const bfrag8*)(BsH + row * 32 + sl);
      bfl[ni] = *(const bfrag8*)(BsL + row * 32 + sl);
    }
#pragma unroll
    for (int mi = 0; mi < 4; ++mi)
#pragma unroll
      for (int ni = 0; ni < 4; ++ni) {
        acc[mi][ni] = __builtin_amdgcn_mfma_f32_16x16x32_bf16(
            afh[mi], bfh[ni], acc[mi][ni], 0, 0, 0);
        acc[mi][ni] = __builtin_amdgcn_mfma_f32_16x16x32_bf16(
            afh[mi], bfl[ni], acc[mi][ni], 0, 0, 0);
        acc[mi][ni] = __builtin_amdgcn_mfma_f32_16x16x32_bf16(
            afl[mi], bfh[ni], acc[mi][ni], 0, 0, 0);
      }
    __syncthreads();
  }
  Cf += (long)bz * NN * NN;
  Ct += (long)bz * NN * NN;
#pragma unroll
  for (int mi = 0; mi < 4; ++mi) {
    int rowb = m0 + wr * 64 + mi * 16 + ((lane >> 4) << 2);
#pragma unroll
    for (int ni = 0; ni < 4; ++ni) {
      int col = n0 + wc * 64 + ni * 16 + (lane & 15);
      float yv = yyb[col];
      float4 tv;
#pragma unroll
      for (int q = 0; q < 4; ++q) {
        float v = xxb[rowb + q] + yv - 2.f * acc[mi][ni][q];
        Cf[(long)(rowb + q) * NN + col] = v;
        ((float*)&tv)[q] = v;
      }
      *(float4*)(Ct + (long)col * NN + rowb) = tv;   // transposed write
    }
  }
}

// ---------------- s0 = cx @ Watt  (per-row dot, HID=128) --------------------
__global__ __launch_bounds__(256) void k_rowdot(const float* __restrict__ X,
                                                const float* __restrict__ w,
                                                float* __restrict__ out) {
  int t = threadIdx.x; int lane = t & 63; int wv = t >> 6;
  int row = blockIdx.x * 4 + wv;
  const float* xr = X + (long)row * HIDN;
  float s = xr[lane] * w[lane] + xr[lane + 64] * w[lane + 64];
  s = wred_sum(s);
  if (lane == 0) out[row] = s;
}

// ---- alpha (4 rows/block) = sigmoid((gcn_norm(adj) @ s0 + batt)^2) ---------
__global__ __launch_bounds__(256) void k_alpha4(const float* __restrict__ adj,
                                                const float* __restrict__ dv,
                                                const float* __restrict__ s0,
                                                const float* __restrict__ batt,
                                                float* __restrict__ alpha) {
  int r0 = blockIdx.x << 2; int b = r0 >> 10; int i0 = r0 & (NN - 1);
  int t = threadIdx.x, lane = t & 63, wv = t >> 6;
  float4 d4 = ((const float4*)(dv + (b << 10)))[t];
  float4 s4 = ((const float4*)(s0 + (b << 10)))[t];
  float w4[4];
  w4[0] = d4.x * s4.x; w4[1] = d4.y * s4.y; w4[2] = d4.z * s4.z; w4[3] = d4.w * s4.w;
  __shared__ float sm[4][4];
#pragma unroll
  for (int r = 0; r < 4; ++r) {
    float4 a4 = ((const float4*)(adj + (long)(r0 + r) * NN))[t];
    float dot = a4.x * w4[0] + a4.y * w4[1] + a4.z * w4[2] + a4.w * w4[3];
    int i = i0 + r;
    if ((i >> 2) == t) dot += w4[i & 3];   // +I diagonal
    dot = wred_sum(dot);
    if (lane == 0) sm[wv][r] = dot;
  }
  __syncthreads();
  if (t < 4) {
    float dot = sm[0][t] + sm[1][t] + sm[2][t] + sm[3][t];
    float tt = dv[r0 + t] * dot + batt[0];
    alpha[r0 + t] = 1.f / (1.f + __expf(-tt * tt));
  }
}

// ---------------- per-batch k-th largest via bitonic sort -------------------
__global__ __launch_bounds__(512) void k_topk(const float* __restrict__ alpha,
                                              float* __restrict__ cut) {
  __shared__ float smv[NN];
  int b = blockIdx.x; int t = threadIdx.x;
  smv[t] = alpha[(b << 10) + t];
  smv[t + 512] = alpha[(b << 10) + t + 512];
  __syncthreads();
  for (int k2 = 2; k2 <= NN; k2 <<= 1) {
    for (int j2 = k2 >> 1; j2 > 0; j2 >>= 1) {
      int i = ((t / j2) * (j2 << 1)) + (t % j2);
      int ixj = i + j2;
      bool up = ((i & k2) == 0);
      float a = smv[i], c = smv[ixj];
      if ((a > c) == up) { smv[i] = c; smv[ixj] = a; }
      __syncthreads();
    }
  }
  if (t == 0) cut[b] = smv[NN - KTOP];
}

// ---- S build (4 rows/block): rmask_i d_i d_j (adj+I) gate_j, row-L1 norm ---
__global__ __launch_bounds__(256) void k_sbuild4(const float* __restrict__ adj,
                                                 const float* __restrict__ dv,
                                                 const float* __restrict__ rm,
                                                 const float* __restrict__ alpha,
                                                 const float* __restrict__ cut,
                                                 float* __restrict__ S) {
  int r0 = blockIdx.x << 2; int b = r0 >> 10; int i0 = r0 & (NN - 1);
  int t = threadIdx.x, lane = t & 63, wv = t >> 6;
  float cb = cut[b];
  float4 d4 = ((const float4*)(dv + (b << 10)))[t];
  float4 al4 = ((const float4*)(alpha + (b << 10)))[t];
  float4 dg;
  dg.x = d4.x * fmaxf(al4.x + 1e-7f - cb, 0.f);
  dg.y = d4.y * fmaxf(al4.y + 1e-7f - cb, 0.f);
  dg.z = d4.z * fmaxf(al4.z + 1e-7f - cb, 0.f);
  dg.w = d4.w * fmaxf(al4.w + 1e-7f - cb, 0.f);
  __shared__ float sm[4][4];
  __shared__ float sinv[4];
  float4 vals[4];
#pragma unroll
  for (int r = 0; r < 4; ++r) {
    float di = dv[r0 + r] * rm[r0 + r];
    float4 a4 = ((const float4*)(adj + (long)(r0 + r) * NN))[t];
    int i = i0 + r;
    if ((i >> 2) == t) ((float*)&a4)[i & 3] += 1.f;
    vals[r].x = di * dg.x * a4.x; vals[r].y = di * dg.y * a4.y;
    vals[r].z = di * dg.z * a4.z; vals[r].w = di * dg.w * a4.w;
    float s = (fabsf(vals[r].x) + fabsf(vals[r].y)) +
              (fabsf(vals[r].z) + fabsf(vals[r].w));
    s = wred_sum(s);
    if (lane == 0) sm[wv][r] = s;
  }
  __syncthreads();
  if (t < 4) sinv[t] = 1.f / fmaxf(sm[0][t] + sm[1][t] + sm[2][t] + sm[3][t], 1e-12f);
  __syncthreads();
#pragma unroll
  for (int r = 0; r < 4; ++r) {
    float inv = sinv[r];
    float4 o; o.x = vals[r].x * inv; o.y = vals[r].y * inv;
    o.z = vals[r].z * inv; o.w = vals[r].w * inv;
    ((float4*)(S + (long)(r0 + r) * NN))[t] = o;
  }
}

// ---------------- K-split fp32 GEMM (TA=0,TB=0), partials out ---------------
template<int GCN>
__global__ __launch_bounds__(256) void k_gemm_ks(
    const float* __restrict__ A, const float* __restrict__ Bm, float* __restrict__ P,
    int M, int Nn, int K, int KS, long sA, long sB,
    const float* __restrict__ dv) {
  __shared__ float As[8][132];
  __shared__ float Bs[8][132];
  int z = blockIdx.z;
  int b = z / KS, ks = z % KS;
  int KC = K / KS;
  A += (long)b * sA; Bm += (long)b * sB;
  const float* dvb = GCN ? (dv + (long)b * NN) : nullptr;
  int m0 = blockIdx.y * 128, n0 = blockIdx.x * 128;
  int tid = threadIdx.x;
  int tx = tid & 15, ty = tid >> 4;
  float acc[8][8];
#pragma unroll
  for (int i = 0; i < 8; i++)
#pragma unroll
    for (int j = 0; j < 8; j++) acc[i][j] = 0.f;

  float drow = 0.f;
  if (GCN) drow = dvb[m0 + (tid >> 1)];

  for (int k0 = ks * KC; k0 < ks * KC + KC; k0 += 8) {
    {
      int r = tid >> 1, c4 = (tid & 1) * 4;
      float4 av = *(const float4*)(A + (long)(m0 + r) * K + k0 + c4);
      float a4[4] = {av.x, av.y, av.z, av.w};
      if (GCN) {
#pragma unroll
        for (int q = 0; q < 4; ++q) {
          int gj = k0 + c4 + q;
          float val = a4[q] + ((m0 + r) == gj ? 1.f : 0.f);
          a4[q] = drow * dvb[gj] * val;
        }
      }
      As[c4 + 0][r] = a4[0]; As[c4 + 1][r] = a4[1];
      As[c4 + 2][r] = a4[2]; As[c4 + 3][r] = a4[3];
    }
    {
      int kr = tid >> 5, c4 = (tid & 31) * 4;
      float4 bv = *(const float4*)(Bm + (long)(k0 + kr) * Nn + n0 + c4);
      *(float4*)&Bs[kr][c4] = bv;
    }
    __syncthreads();
#pragma unroll
    for (int k = 0; k < 8; ++k) {
      float av[8], bv[8];
      *(float4*)&av[0] = *(const float4*)&As[k][ty * 8];
      *(float4*)&av[4] = *(const float4*)&As[k][ty * 8 + 4];
      *(float4*)&bv[0] = *(const float4*)&Bs[k][tx * 8];
      *(float4*)&bv[4] = *(const float4*)&Bs[k][tx * 8 + 4];
#pragma unroll
      for (int i = 0; i < 8; i++)
#pragma unroll
        for (int j = 0; j < 8; j++)
          acc[i][j] = fmaf(av[i], bv[j], acc[i][j]);
    }
    __syncthreads();
  }
  float* Pz = P + (long)z * M * Nn;
#pragma unroll
  for (int i = 0; i < 8; ++i) {
    int m = m0 + ty * 8 + i;
    float* prow = Pz + (long)m * Nn + n0 + tx * 8;
    *(float4*)&prow[0] = *(float4*)&acc[i][0];
    *(float4*)&prow[4] = *(float4*)&acc[i][4];
  }
}

// ---------------- reduce K-split partials (+bias, +relu) --------------------
template<int RELU, int BIAS>
__global__ __launch_bounds__(256) void k_red_bias(
    const float* __restrict__ P, const float* __restrict__ bias,
    float* __restrict__ out, int Nn, int KS, long chunk) {
  long u = ((long)blockIdx.x * 256 + threadIdx.x) * 4;
  long b = u / chunk; long rem = u % chunk;
  const float* p = P + b * KS * chunk + rem;
  float4 s = *(const float4*)p;
  for (int k = 1; k < KS; ++k) {
    float4 q = *(const float4*)(p + (long)k * chunk);
    s.x += q.x; s.y += q.y; s.z += q.z; s.w += q.w;
  }
  if (BIAS) {
    int n = (int)(rem % Nn);
    s.x += bias[n]; s.y += bias[n + 1]; s.z += bias[n + 2]; s.w += bias[n + 3];
  }
  if (RELU) {
    s.x = fmaxf(s.x, 0.f); s.y = fmaxf(s.y, 0.f);
    s.z = fmaxf(s.z, 0.f); s.w = fmaxf(s.w, 0.f);
  }
  *(float4*)(out + u) = s;
}

// ---------------- column mean over nodes ------------------------------------
__global__ __launch_bounds__(256) void k_colmean(const float* __restrict__ X, int Fd,
                                                 float* __restrict__ out) {
  int nb = Fd >> 6;
  int b = blockIdx.x / nb; int f0 = (blockIdx.x % nb) << 6;
  int t = threadIdx.x;
  int f = f0 + (t & 63); int rc = t >> 6;
  const float* xb = X + (long)b * NN * Fd;
  float s = 0.f;
  for (int i = rc * 256; i < rc * 256 + 256; ++i) s += xb[(long)i * Fd + f];
  __shared__ float sm[256];
  sm[t] = s; __syncthreads();
  if (t < 64) out[b * Fd + f] = (sm[t] + sm[t + 64] + sm[t + 128] + sm[t + 192]) * (1.f / NN);
}

// ======================= persistent register-resident Sinkhorn ==============
// Fence-free sync (sc0/sc1 write-through + relaxed flags) as round 8, plus:
// - XCD-local groups: grp = bid & 7 (heuristic: bid%8 -> same XCD), so slot
//   polling stays in one XCD's L2.
// - dual slice loaded LDS->registers ONCE per pass (halves ds_read traffic).

static __device__ __forceinline__ float4 load_cohere4(const float* p) {
  float4 v;
  asm volatile("global_load_dwordx4 %0, %1, off sc0 sc1\n\ts_waitcnt vmcnt(0)"
               : "=v"(v) : "v"(p) : "memory");
  return v;
}
static __device__ __forceinline__ float load_cohere1(const float* p) {
  float v;
  asm volatile("global_load_dword %0, %1, off sc0 sc1\n\ts_waitcnt vmcnt(0)"
               : "=v"(v) : "v"(p) : "memory");
  return v;
}
static __device__ __forceinline__ void store_cohere1(float* p, float v) {
  asm volatile("global_store_dword %0, %1, off sc0 sc1\n\ts_waitcnt vmcnt(0)"
               :: "v"(p), "v"(v) : "memory");
}

static __device__ __forceinline__ void stage_vec(float* __restrict__ vls,
                                                 const float* __restrict__ src,
                                                 int t) {
  if (t < 256) {
    float4 v = load_cohere4(src + t * 4);
    *(float4*)(vls + t * 4) = v;
  }
  __syncthreads();
}

static __device__ __forceinline__ void group_bar(int* __restrict__ slots,
                                                 int bid, int grp, int t, int g1) {
  __syncthreads();   // all waves' data stores done (vmcnt drained in-asm)
  if (t == 0)
    __hip_atomic_store(&slots[bid * 16], g1, __ATOMIC_RELAXED,
                       __HIP_MEMORY_SCOPE_AGENT);
  if (t < 32) {
    int idx = ((t << 3) + grp) * 16;   // blocks {8t+grp}: XCD-local set
    int spin = 0;
    while (__hip_atomic_load(&slots[idx], __ATOMIC_RELAXED,
                             __HIP_MEMORY_SCOPE_AGENT) < g1) {
      if (++spin > (1 << 20)) break;
      __builtin_amdgcn_s_sleep(1);
    }
  }
  __syncthreads();
}

// One LSE half-pass for this lane's interleaved row slice.
template<int LOSS>
static __device__ __forceinline__ void pass_reg(const float4 (&Cr)[16],
    const float* __restrict__ vls, float* __restrict__ uout,
    int jc, int row, float* __restrict__ lossacc) {
  float4 vr[16];
#pragma unroll
  for (int k = 0; k < 16; ++k)
    vr[k] = *(const float4*)(vls + (k * 16 + jc) * 4);
  float mx = -3.0e38f;
#pragma unroll
  for (int k = 0; k < 16; ++k) {
    float ax = vr[k].x - Cr[k].x, ay = vr[k].y - Cr[k].y;
    float az = vr[k].z - Cr[k].z, aw = vr[k].w - Cr[k].w;
    mx = fmaxf(mx, fmaxf(fmaxf(ax, ay), fmaxf(az, aw)));
  }
#pragma unroll
  for (int m = 1; m <= 8; m <<= 1) mx = fmaxf(mx, __shfl_xor(mx, m));
  float ls = 0.f, ld = 0.f;
#pragma unroll
  for (int k = 0; k < 16; ++k) {
    float e;
    e = __expf(vr[k].x - Cr[k].x - mx); ls += e; if (LOSS) ld = fmaf(e, Cr[k].x, ld);
    e = __expf(vr[k].y - Cr[k].y - mx); ls += e; if (LOSS) ld = fmaf(e, Cr[k].y, ld);
    e = __expf(vr[k].z - Cr[k].z - mx); ls += e; if (LOSS) ld = fmaf(e, Cr[k].z, ld);
    e = __expf(vr[k].w - Cr[k].w - mx); ls += e; if (LOSS) ld = fmaf(e, Cr[k].w, ld);
  }
#pragma unroll
  for (int m = 1; m <= 8; m <<= 1) {
    ls += __shfl_xor(ls, m);
    if (LOSS) ld += __shfl_xor(ld, m);
  }
  if (jc == 0) {
    float uval = LOG_MU - (mx + __logf(ls));   // scaled dual u/eps
    store_cohere1(uout + row, uval);
    if (LOSS) *lossacc += (ld / ls) * (1.0f / 1024.0f);
  }
}

__global__ __launch_bounds__(512, 2) void k_sink_reg(
    const float* __restrict__ Cm, const float* __restrict__ Ct,
    float* __restrict__ uvv, float* __restrict__ vvv,
    float* __restrict__ part, float* __restrict__ oloss,
    int* __restrict__ slots1, int* __restrict__ slots2) {
  int bid = blockIdx.x, t = threadIdx.x, lane = t & 63, wvi = t >> 6;
  int jc = lane & 15;
  int grp = bid & 7;          // batch index; bid%8 keeps a group on one XCD
  int inner = bid >> 3;       // 0..31
  int row = (grp << 10) + inner * 32 + wvi * 4 + (lane >> 4);
  __shared__ float vls[1024];
  float4 Creg[16], Ctreg[16];
  {
    const float4* cp = (const float4*)(Cm + (long)row * NN);
    const float4* tp = (const float4*)(Ct + (long)row * NN);
#pragma unroll
    for (int k = 0; k < 16; ++k) {
      float4 c = cp[k * 16 + jc], ct = tp[k * 16 + jc];
      Creg[k].x = c.x * INV_EPS;  Creg[k].y = c.y * INV_EPS;
      Creg[k].z = c.z * INV_EPS;  Creg[k].w = c.w * INV_EPS;
      Ctreg[k].x = ct.x * INV_EPS; Ctreg[k].y = ct.y * INV_EPS;
      Ctreg[k].z = ct.z * INV_EPS; Ctreg[k].w = ct.w * INV_EPS;
    }
  }
  const float* ub = uvv + (grp << 10);
  const float* vb = vvv + (grp << 10);
  float lossacc = 0.f;
  int g1 = 1;
  for (int it = 0; it < NITER; ++it) {
    stage_vec(vls, vb, t);                                 // v -> LDS
    pass_reg<0>(Creg, vls, uvv, jc, row, nullptr);         // u update
    group_bar(slots1, bid, grp, t, g1); ++g1;
    stage_vec(vls, ub, t);                                 // u -> LDS
    if (it < NITER - 1) {
      pass_reg<0>(Ctreg, vls, vvv, jc, row, nullptr);      // v update
      group_bar(slots1, bid, grp, t, g1); ++g1;
    } else {
      pass_reg<1>(Ctreg, vls, vvv, jc, row, &lossacc);     // v + fused loss
    }
  }
  // per-block loss partial
  float s = wred_sum(lossacc);
  __shared__ float lsm[8];
  if (lane == 0) lsm[wvi] = s;
  __syncthreads();
  if (t == 0) {
    float ps = 0.f;
#pragma unroll
    for (int i = 0; i < 8; ++i) ps += lsm[i];
    store_cohere1(part + bid, ps);
    __hip_atomic_store(&slots2[bid * 16], 1, __ATOMIC_RELAXED,
                       __HIP_MEMORY_SCOPE_AGENT);
  }
  if (bid == 0) {
    if (t < SNB) {
      int spin = 0;
      while (__hip_atomic_load(&slots2[t * 16], __ATOMIC_RELAXED,
                               __HIP_MEMORY_SCOPE_AGENT) < 1) {
        if (++spin > (1 << 20)) break;
        __builtin_amdgcn_s_sleep(1);
      }
    }
    __syncthreads();
    float s2 = 0.f;
    if (t < SNB) s2 = load_cohere1(part + t);
    s2 = wred_sum(s2);
    __shared__ float sm2[8];
    if (lane == 0) sm2[wvi] = s2;
    __syncthreads();
    if (t == 0) {
      float tot = 0.f;
#pragma unroll
      for (int i = 0; i < 8; ++i) tot += sm2[i];
      oloss[0] = tot * EPS_S;   // undo the 1/eps scaling of C' in ld
    }
  }
}

extern "C" void kernel_launch(void* const* d_in, const int* in_sizes, int n_in,
                              void* d_out, int out_size, void* d_ws, size_t ws_size,
                              hipStream_t stream) {
  const float* x    = (const float*)d_in[0];
  const float* adj  = (const float*)d_in[1];
  const float* W1   = (const float*)d_in[3];
  const float* b1   = (const float*)d_in[4];
  const float* Watt = (const float*)d_in[5];
  const float* batt = (const float*)d_in[6];
  const float* W2   = (const float*)d_in[7];
  const float* b2   = (const float*)d_in[8];

  float* out = (float*)d_out;
  float* xs0   = out;                    // [8,128]
  float* xs1   = out + 1024;             // [8,256]
  float* oadj0 = out + 3072;             // [8,1024,1024]
  float* oadj1 = oadj0 + 8388608;
  float* oadj2 = oadj1 + 8388608;        // adj_bf scratch until adj2 written
  float* oS0   = oadj2 + 8388608;
  float* oS1   = oS0 + 8388608;
  float* oloss = oS1 + 8388608;          // [1]

  float* ws   = (float*)d_ws;
  float* wXW  = ws;                       // 2,097,152 (XW1 then XW2)
  float* wCXA = wXW + 2097152;            // 1,048,576 (x1, later emb2)
  float* wCXB = wCXA + 1048576;           // 1,048,576 (emb1)
  float* wR   = wCXB + 1048576;           // 8,388,608 (tmp_bf | P | Cmat)
  float* wX2  = wR + 8388608;             // 2,097,152 (x2)
  float* wStf = wX2 + 2097152;            // 4,194,304 (x_bf/St/Bg2/x-splits)
  float* wCxtf= wStf + 4194304;           // 524,288   (Bg1 / cxt)
  float* wCt  = wCxtf + 524288;           // 8,388,608 (a2h+a2l, then C^T)
  float* smb  = wCt + 8388608;

  unsigned short* tmp_bf = (unsigned short*)wR;                 // 16.7MB half
  unsigned short* a2h    = (unsigned short*)wCt;                // 8,388,608 sh
  unsigned short* a2l    = a2h + 8388608;                       // 8,388,608 sh
  unsigned short* adj_bf = (unsigned short*)oadj2;
  unsigned short* St     = (unsigned short*)wStf;
  unsigned short* cxt    = (unsigned short*)wCxtf;
  unsigned short* x_bf   = (unsigned short*)wStf;               // pre-coarsen
  unsigned short* Bg1    = (unsigned short*)wCxtf;
  unsigned short* Bg2h   = (unsigned short*)wStf;               // post-adj2
  unsigned short* Bg2l   = (unsigned short*)(wStf + 2097152);
  unsigned short* xh  = (unsigned short*)wStf;                  // sinkhorn phase
  unsigned short* xl  = xh + 2097152;
  unsigned short* x2h = xh + 4194304;
  unsigned short* x2l = xh + 6291456;
  float* Cmat = wR;
  float* d0 = smb;            float* rm0 = smb + 8192;
  float* d1 = smb + 16384;    float* rm1 = smb + 24576;
  float* d2 = smb + 32768;    float* rm2 = smb + 40960;
  float* s0v = smb + 49152;   float* alp = smb + 57344;
  float* xxv = smb + 65536;   float* yyv = smb + 73728;
  float* uv  = smb + 81920;   float* vv  = smb + 90112;   // contiguous
  float* cutv = smb + 98304;  float* part = smb + 98368;  // 256
  unsigned short* W1t = (unsigned short*)(smb + 98624);    // 32768 shorts
  int* ibar = (int*)(smb + 115008);
  int* slots1 = ibar;                 // 256*16 ints
  int* slots2 = ibar + 4096;          // 256*16 ints

  // rowstats on adj + fused bf16 copy (into oadj2 region) + fp32 copy (oadj0)
  k_rowstats4<1, 1><<<2048, 256, 0, stream>>>(adj, d0, rm0, adj_bf, oadj0);

  // ---- GCN1 (MFMA): x1 = relu(d*(adj_bf @ (d.*XW1) + d*XW1_diag) + b1) ----
  k_f2b<<<2048, 256, 0, stream>>>(x, x_bf);
  k_w1t<<<128, 256, 0, stream>>>(W1, W1t);
  k_mfma_nt<1, 0><<<dim3(1, 64, 1), 256, 0, stream>>>(x_bf, W1t, wXW, nullptr,
      nullptr, 256, 256, 256, 128, 0L, 0L, 0L);
  k_stc<0><<<dim3(16, 2, 8), 256, 0, stream>>>(wXW, d0, Bg1, nullptr, HIDN);
  k_mfma_gcn<0, 1><<<dim3(1, 8, 8), 256, 0, stream>>>(adj_bf, nullptr, Bg1,
      nullptr, d0, wXW, b1, wCXA, HIDN);
  k_colmean<<<16, 256, 0, stream>>>(wCXA, HIDN, xs0);

  // ---- coarsen layer 1 ----
  k_rowdot<<<2048, 256, 0, stream>>>(wCXA, Watt, s0v);
  k_alpha4<<<2048, 256, 0, stream>>>(adj, d0, s0v, batt, alp);
  k_topk<<<8, 512, 0, stream>>>(alp, cutv);
  k_sbuild4<<<2048, 256, 0, stream>>>(adj, d0, rm0, alp, cutv, oS0);
  k_transp<<<dim3(16, 16, 8), 256, 0, stream>>>(oS0, St, 1024, 1024);
  k_transp<<<dim3(2, 16, 8), 256, 0, stream>>>(wCXA, cxt, 1024, 128);
  // merged: tmp = St*adj (bx<8) and emb1 = St*cxt (bx==8)
  k_coars<<<dim3(9, 8, 8), 256, 0, stream>>>(St, adj_bf, cxt, tmp_bf, wCXB);
  k_mfma_nt<1, 1><<<dim3(8, 8, 8), 256, 0, stream>>>(tmp_bf, St, oadj1, adj_bf,
      nullptr, 1024, 1024, 1024, 1024, 1048576L, 1048576L, 1048576L);
  k_rowstats4<0, 0><<<2048, 256, 0, stream>>>(oadj1, d1, rm1, nullptr, nullptr);

  // ---- coarsen layer 2 ----
  k_rowdot<<<2048, 256, 0, stream>>>(wCXB, Watt, s0v);
  k_alpha4<<<2048, 256, 0, stream>>>(oadj1, d1, s0v, batt, alp);
  k_topk<<<8, 512, 0, stream>>>(alp, cutv);
  k_sbuild4<<<2048, 256, 0, stream>>>(oadj1, d1, rm1, alp, cutv, oS1);
  k_transp<<<dim3(16, 16, 8), 256, 0, stream>>>(oS1, St, 1024, 1024);
  k_transp<<<dim3(2, 16, 8), 256, 0, stream>>>(wCXB, cxt, 1024, 128);
  // merged: tmp = St*adj1 (bx<8) and emb2 = St*cxt (bx==8)
  k_coars<<<dim3(9, 8, 8), 256, 0, stream>>>(St, adj_bf, cxt, tmp_bf, wCXA);
  // adj2 -> fp32 output + hi/lo bf16 pair (in wCt region) for split final GCN
  k_mfma_nt<1, 2><<<dim3(8, 8, 8), 256, 0, stream>>>(tmp_bf, St, oadj2, a2h,
      a2l, 1024, 1024, 1024, 1024, 1048576L, 1048576L, 1048576L);
  k_rowstats4<0, 0><<<2048, 256, 0, stream>>>(oadj2, d2, rm2, nullptr, nullptr);

  // ---- final GCN (split-bf16 MFMA): x2 = d*(A2@(d.*XW2) + d*XW2_diag) + b2 --
  k_gemm_ks<0><<<dim3(2, 64, 2), 256, 0, stream>>>(wCXA, W2, wR, 8192, FIN, HIDN,
      2, 0L, 0L, nullptr);   // P partials in wR first half (tmp_bf dead)
  k_red_bias<0, 0><<<2048, 256, 0, stream>>>(wR, nullptr, wXW, FIN, 2, 2097152L);
  k_stc<1><<<dim3(16, 4, 8), 256, 0, stream>>>(wXW, d2, Bg2h, Bg2l, FIN);
  k_mfma_gcn<1, 0><<<dim3(2, 8, 8), 256, 0, stream>>>(a2h, a2l, Bg2h, Bg2l,
      d2, wXW, b2, wX2, FIN);
  k_colmean<<<32, 256, 0, stream>>>(wX2, FIN, xs1);

  // ---- Sinkhorn: C via split-bf16 MFMA Gram (+fused C^T), reg-resident solve
  k_prep<<<2048, 256, 0, stream>>>(x, xh, xl, xxv);
  k_prep<<<2048, 256, 0, stream>>>(wX2, x2h, x2l, yyv);
  k_mfma_gram<<<dim3(8, 8, 8), 256, 0, stream>>>(xh, xl, x2h, x2l, xxv, yyv,
      Cmat, wCt);
  hipMemsetAsync(uv, 0, (size_t)2 * 8192 * 4, stream);
  hipMemsetAsync(ibar, 0, (size_t)8192 * 4, stream);
  k_sink_reg<<<SNB, 512, 0, stream>>>(Cmat, wCt, uv, vv, part, oloss,
                                      slots1, slots2);
}